// Round 15
// baseline (177.714 us; speedup 1.0000x reference)
//
#include <hip/hip_runtime.h>
#include <hip/hip_fp16.h>

// AttentionQV0: LN -> QKV -> [QK^T + dw-convs fused] -> [1x1+BN+SiLU+softmax+PV fused] -> out proj
// B=2,P=2,N=1024,DIM=256,HEADS=8,DH=64,HW=32,C=1024. 32 "images" of 1024x1024 scores.
// D never hits HBM (conv in QK epilogue); P never hits HBM (PV in 1x1 epilogue).
// P LDS layout uses address-chunk XOR swizzle (mm ^ ((mm>>7)&7)<<4): the 4 kq write
// groups land on disjoint bank octets (conflict-free); reads XOR by (ph<<4).
// AC uses a permuted channel axis c' = (bx*4+by)*32 + a*8 + b; W1X1H K-permuted to match.

#define DEV __device__ __forceinline__

typedef __attribute__((ext_vector_type(8))) _Float16 f16x8;
typedef __attribute__((ext_vector_type(4))) float f32x4;
typedef __attribute__((ext_vector_type(8))) unsigned short u16x8;

DEV float h2f_bits(unsigned short u) { __half h; *reinterpret_cast<unsigned short*>(&h) = u; return __half2float(h); }
DEV unsigned short f2h_bits(float f) { __half h = __float2half(f); return *reinterpret_cast<unsigned short*>(&h); }

// ---------------- prep: W1X1 permuted cast only ----------------
__global__ __launch_bounds__(256) void prep_kernel(
    const float* __restrict__ w1x1, __half* __restrict__ W1X1H) {
  int i0 = blockIdx.x * 256 + threadIdx.x;
  int stride = gridDim.x * 256;
  for (int i = i0; i < 1024 * 1024; i += stride) {         // permuted K axis: col p -> c(p)
    int o = i >> 10, p = i & 1023;
    int blk = p >> 5, r = p & 31, a = r >> 3, bb = r & 7;
    int h1 = (blk >> 2) * 4 + a, h2 = (blk & 3) * 8 + bb;
    W1X1H[i] = __float2half(w1x1[o * 1024 + h1 * 32 + h2]);
  }
}

// ---------------- transpose-cast: dst[c][r] f16 = src[r][c] f32, 64x64 LDS tiles ----------------
__global__ __launch_bounds__(256) void tcast_kernel(const float* __restrict__ src,
    __half* __restrict__ dst, int R, int C) {
  __shared__ __half T[64][80];                 // row stride 160B (16B-aligned)
  const int r0 = blockIdx.x * 64, c0 = blockIdx.y * 64;
  {
    int rr = threadIdx.x >> 2, cq = (threadIdx.x & 3) * 16;
    const float4* s = reinterpret_cast<const float4*>(src + (size_t)(r0 + rr) * C + c0 + cq);
#pragma unroll
    for (int u = 0; u < 4; ++u) {
      float4 f = s[u];
      T[cq + u * 4 + 0][rr] = __float2half(f.x);
      T[cq + u * 4 + 1][rr] = __float2half(f.y);
      T[cq + u * 4 + 2][rr] = __float2half(f.z);
      T[cq + u * 4 + 3][rr] = __float2half(f.w);
    }
  }
  __syncthreads();
  {
    int cc = threadIdx.x >> 2, rq = (threadIdx.x & 3) * 16;
    __half* d = dst + (size_t)(c0 + cc) * R + r0 + rq;
    *reinterpret_cast<u16x8*>(d)     = *reinterpret_cast<const u16x8*>(&T[cc][rq]);
    *reinterpret_cast<u16x8*>(d + 8) = *reinterpret_cast<const u16x8*>(&T[cc][rq + 8]);
  }
}

// ---------------- LayerNorm (row = token, 256 threads) ----------------
__global__ __launch_bounds__(256) void ln_kernel(const float* __restrict__ x,
    const float* __restrict__ g, const float* __restrict__ b, __half* __restrict__ XN) {
  int row = blockIdx.x;
  int tid = threadIdx.x, lane = tid & 63, wid = tid >> 6;
  float xv = x[(size_t)row * 256 + tid];
  float s = xv, q = xv * xv;
#pragma unroll
  for (int off = 32; off; off >>= 1) { s += __shfl_xor(s, off); q += __shfl_xor(q, off); }
  __shared__ float rs[4], rq[4];
  if (lane == 0) { rs[wid] = s; rq[wid] = q; }
  __syncthreads();
  s = rs[0] + rs[1] + rs[2] + rs[3];
  q = rq[0] + rq[1] + rq[2] + rq[3];
  float mu = s * (1.f / 256.f);
  float var = q * (1.f / 256.f) - mu * mu;
  float r = rsqrtf(var + 1e-5f);
  XN[(size_t)row * 256 + tid] = __float2half((xv - mu) * r * g[tid] + b[tid]);
}

// ---------------- QKV GEMM (dedicated): 128x128, BK=64, 4 waves ----------------
__global__ __launch_bounds__(256) void gemm_qkv(
    const __half* __restrict__ A, const __half* __restrict__ B,
    __half* __restrict__ Q, __half* __restrict__ Ko, __half* __restrict__ Vt) {
  constexpr int BK = 64, K = 256;
  __shared__ __align__(16) char RAW[65536];
  __half* smA = (__half*)RAW;                  // [2][128*64] 32KB
  __half* smB = (__half*)(RAW + 32768);        // [2][128*64] 32KB
  __half* Tld = (__half*)RAW;                  // [128][136] 34.8KB (epilogue alias)
  const int tid = threadIdx.x;
  const int lane = tid & 63, wid = tid >> 6;
  const int wr = wid >> 1, wc = wid & 1;
  const int gx = gridDim.x;
  const int nwg = gx * gridDim.y;
  const int b_lin = blockIdx.x + blockIdx.y * gx;
  const int logical = (b_lin & 7) * (nwg >> 3) + (b_lin >> 3);
  const int bx = logical % gx, by = logical / gx;
  const int row0 = bx * 128, col0 = by * 128;
  f32x4 acc[4][4] = {};
  const int lr = lane & 15;
  const int kq = lane >> 4;

  const __half* pA[4]; int dA[4];
  const __half* pB[4]; int dB[4];
#pragma unroll
  for (int it = 0; it < 4; ++it) {
    int e = it * 256 + tid, r = e >> 3, c = e & 7, sc = c ^ (r & 7);
    pA[it] = A + (size_t)(row0 + r) * K + sc * 8;
    pB[it] = B + (size_t)(col0 + r) * K + sc * 8;
    dA[it] = dB[it] = r * BK + c * 8;
  }
  auto stage = [&](int buf, int kt) {
#pragma unroll
    for (int it = 0; it < 4; ++it)
      __builtin_amdgcn_global_load_lds(
          (const __attribute__((address_space(1))) unsigned int*)(pA[it] + kt),
          (__attribute__((address_space(3))) unsigned int*)(&smA[buf * 8192 + dA[it]]),
          16, 0, 0);
#pragma unroll
    for (int it = 0; it < 4; ++it)
      __builtin_amdgcn_global_load_lds(
          (const __attribute__((address_space(1))) unsigned int*)(pB[it] + kt),
          (__attribute__((address_space(3))) unsigned int*)(&smB[buf * 8192 + dB[it]]),
          16, 0, 0);
  };

  const int NT = K / BK;                       // 4
  stage(0, 0);
  __syncthreads();
  int cur = 0;
  for (int t = 0; t < NT; ++t) {
    if (t + 1 < NT) stage(cur ^ 1, (t + 1) * BK);
#pragma unroll
    for (int kk = 0; kk < 2; ++kk) {
      f16x8 av[4], bv[4];
#pragma unroll
      for (int i = 0; i < 4; ++i) {
        int row = wr * 64 + i * 16 + lr;
        int ch = (kk * 4 + kq) ^ (lr & 7);
        av[i] = *reinterpret_cast<const f16x8*>(&smA[cur * 8192 + row * BK + ch * 8]);
      }
#pragma unroll
      for (int j = 0; j < 4; ++j) {
        int row = wc * 64 + j * 16 + lr;
        int ch = (kk * 4 + kq) ^ (lr & 7);
        bv[j] = *reinterpret_cast<const f16x8*>(&smB[cur * 8192 + row * BK + ch * 8]);
      }
#pragma unroll
      for (int i = 0; i < 4; ++i)
#pragma unroll
        for (int j = 0; j < 4; ++j)
          acc[i][j] = __builtin_amdgcn_mfma_f32_16x16x32_f16(av[i], bv[j], acc[i][j], 0, 0, 0);
    }
    __syncthreads();
    cur ^= 1;
  }

  const int bp = row0 >> 10, n0 = row0 & 1023;
  if (by < 8) {
#pragma unroll
    for (int i = 0; i < 4; ++i)
#pragma unroll
      for (int j = 0; j < 4; ++j)
#pragma unroll
        for (int q = 0; q < 4; ++q) {
          int t = row0 + wr * 64 + i * 16 + kq * 4 + q;
          int jj = col0 + wc * 64 + j * 16 + lr;
          int part = jj >> 9, inner = jj & 511;
          int h = inner >> 6, d = inner & 63;
          int n = t & 1023;
          size_t img = (size_t)((t >> 10) * 8 + h);
          float v = acc[i][j][q];
          if (part == 0) Q[(img * 1024 + n) * 64 + d] = __float2half(v * 0.125f);
          else           Ko[(img * 1024 + n) * 64 + d] = __float2half(v);
        }
  } else {
#pragma unroll
    for (int i = 0; i < 4; ++i)
#pragma unroll
      for (int j = 0; j < 4; ++j)
#pragma unroll
        for (int q = 0; q < 4; ++q) {
          int nl = wr * 64 + i * 16 + kq * 4 + q;
          int jl = wc * 64 + j * 16 + lr;
          int ch = (nl >> 3) ^ (jl & 7);
          Tld[jl * 136 + ch * 8 + (nl & 7)] = __float2half(acc[i][j][q]);
        }
    __syncthreads();
    const int jl = tid >> 1, hf = tid & 1;
    const int d = jl & 63;
    const int vimg = bp * 8 + (by - 8) * 2 + (jl >> 6);
    __half* dst = Vt + ((size_t)(vimg * 64 + d)) * 1024 + n0 + hf * 64;
#pragma unroll
    for (int u = 0; u < 8; ++u) {
      int cidx = (hf * 8 + u) ^ (jl & 7);
      *reinterpret_cast<u16x8*>(dst + u * 8) =
          *reinterpret_cast<const u16x8*>(Tld + jl * 136 + cidx * 8);
    }
  }
}

// ---------------- out-proj GEMM (generic BT, 4 waves) ----------------
struct EpiOut {
  float* out; const float* bias;
  DEV void store(int, int t, int j, float v) const {
    out[(size_t)t * 256 + j] = v + bias[j];
  }
};

template <int BM, int BN, int BK, int WGN, int FM, int FN, class Epi>
__global__ __launch_bounds__(256) void gemm_bt(
    const __half* __restrict__ A, long long aStride,
    const __half* __restrict__ B, long long bStride,
    int K, Epi epi) {
  constexpr int CPR = BK / 8;
  constexpr int NCA = (BM * BK) / (8 * 256);
  constexpr int NCB = (BN * BK) / (8 * 256);
  constexpr int KSUB = BK / 32;
  __shared__ __align__(16) __half smA[2][BM * BK];
  __shared__ __align__(16) __half smB[2][BN * BK];
  const int tid = threadIdx.x;
  const int lane = tid & 63, wid = tid >> 6;
  const int wr = wid / WGN, wc = wid % WGN;
  const int gx = gridDim.x, gxy = gridDim.x * gridDim.y;
  const int nwg = gxy * gridDim.z;
  const int b_lin = blockIdx.x + blockIdx.y * gx + blockIdx.z * gxy;
  const int logical = (b_lin & 7) * (nwg >> 3) + (b_lin >> 3);
  const int bx = logical % gx, by = (logical / gx) % gridDim.y, bz = logical / gxy;
  const int img = bz;
  const int row0 = bx * BM;
  const int col0 = by * BN;
  const __half* Ab = A + (size_t)((long long)img * aStride);
  const __half* Bb = B + (size_t)((long long)img * bStride);
  f32x4 acc[FM][FN] = {};
  const int lr = lane & 15;
  const int kq = lane >> 4;

  auto swz = [](int c, int r) -> int {
    return (CPR == 8) ? (c ^ (r & 7)) : (c ^ ((r >> 1) & 3));
  };

  const __half* pA[NCA]; int dA[NCA];
  const __half* pB[NCB]; int dB[NCB];
#pragma unroll
  for (int it = 0; it < NCA; ++it) {
    int e = it * 256 + tid, r = e / CPR, c = e % CPR;
    pA[it] = Ab + (size_t)(row0 + r) * K + swz(c, r) * 8;
    dA[it] = r * BK + c * 8;
  }
#pragma unroll
  for (int it = 0; it < NCB; ++it) {
    int e = it * 256 + tid, r = e / CPR, c = e % CPR;
    pB[it] = Bb + (size_t)(col0 + r) * K + swz(c, r) * 8;
    dB[it] = r * BK + c * 8;
  }

  auto stage = [&](int buf, int kt) {
#pragma unroll
    for (int it = 0; it < NCA; ++it)
      __builtin_amdgcn_global_load_lds(
          (const __attribute__((address_space(1))) unsigned int*)(pA[it] + kt),
          (__attribute__((address_space(3))) unsigned int*)(&smA[buf][dA[it]]),
          16, 0, 0);
#pragma unroll
    for (int it = 0; it < NCB; ++it)
      __builtin_amdgcn_global_load_lds(
          (const __attribute__((address_space(1))) unsigned int*)(pB[it] + kt),
          (__attribute__((address_space(3))) unsigned int*)(&smB[buf][dB[it]]),
          16, 0, 0);
  };

  const int NT = K / BK;
  stage(0, 0);
  __syncthreads();
  int cur = 0;
  for (int t = 0; t < NT; ++t) {
    if (t + 1 < NT) stage(cur ^ 1, (t + 1) * BK);
#pragma unroll
    for (int kk = 0; kk < KSUB; ++kk) {
      f16x8 av[FM], bv[FN];
#pragma unroll
      for (int i = 0; i < FM; ++i) {
        int row = wr * FM * 16 + i * 16 + lr;
        int ch = swz(kk * 4 + kq, lr);
        av[i] = *reinterpret_cast<const f16x8*>(&smA[cur][row * BK + ch * 8]);
      }
#pragma unroll
      for (int j = 0; j < FN; ++j) {
        int row = wc * FN * 16 + j * 16 + lr;
        int ch = swz(kk * 4 + kq, lr);
        bv[j] = *reinterpret_cast<const f16x8*>(&smB[cur][row * BK + ch * 8]);
      }
#pragma unroll
      for (int i = 0; i < FM; ++i)
#pragma unroll
        for (int j = 0; j < FN; ++j)
          acc[i][j] = __builtin_amdgcn_mfma_f32_16x16x32_f16(av[i], bv[j], acc[i][j], 0, 0, 0);
    }
    __syncthreads();
    cur ^= 1;
  }

  const int orow = row0 + wr * FM * 16 + (lane >> 4) * 4;
  const int ocol = col0 + wc * FN * 16 + lr;
#pragma unroll
  for (int i = 0; i < FM; ++i)
#pragma unroll
    for (int j = 0; j < FN; ++j)
#pragma unroll
      for (int q = 0; q < 4; ++q)
        epi.store(img, orow + i * 16 + q, ocol + j * 16, acc[i][j][q]);
}

// ---------------- fused QK^T + depthwise convs ----------------
__global__ __launch_bounds__(512) void qkconv_kernel(
    const __half* __restrict__ Q, const __half* __restrict__ Km,
    const float* __restrict__ wc1, const float* __restrict__ wc2,
    __half* __restrict__ AC) {
  constexpr int NP = 132;                       // Dt inner pad (halfs)
  __shared__ __align__(16) char LDS[77824];     // max(stage 48K, Dt 66K) + T 10K
  __half* smA = (__half*)LDS;                   // [128][64]  16384 B
  __half* smB = (__half*)(LDS + 16384);         // [256][64]  32768 B
  __half* Dt  = (__half*)LDS;                   // [256][132] 67584 B (aliases stage)
  __half* T   = (__half*)(LDS + 67584);         // [4][32][40] 10240 B
  const int tid = threadIdx.x;
  const int lane = tid & 63, wid = tid >> 6;
  const int wr = wid >> 2, wc = wid & 3;
  const int gx = gridDim.x, gxy = gx * gridDim.y;
  const int nwg = gxy * gridDim.z;
  const int b_lin = blockIdx.x + blockIdx.y * gx + blockIdx.z * gxy;
  const int logical = (b_lin & 7) * (nwg >> 3) + (b_lin >> 3);
  const int bx = logical % gx, by = (logical / gx) % gridDim.y, bz = logical / gxy;
  const int img = bz, row0 = bx * 128, col0 = by * 256;
  const __half* Qi = Q + ((size_t)img << 16);
  const __half* Ki = Km + ((size_t)img << 16);

#pragma unroll
  for (int it = 0; it < 2; ++it) {
    int e = it * 512 + tid, r = e >> 3, c = e & 7, sc = c ^ (r & 7);
    __builtin_amdgcn_global_load_lds(
        (const __attribute__((address_space(1))) unsigned int*)(Qi + (size_t)(row0 + r) * 64 + sc * 8),
        (__attribute__((address_space(3))) unsigned int*)(smA + r * 64 + c * 8), 16, 0, 0);
  }
#pragma unroll
  for (int it = 0; it < 4; ++it) {
    int e = it * 512 + tid, r = e >> 3, c = e & 7, sc = c ^ (r & 7);
    __builtin_amdgcn_global_load_lds(
        (const __attribute__((address_space(1))) unsigned int*)(Ki + (size_t)(col0 + r) * 64 + sc * 8),
        (__attribute__((address_space(3))) unsigned int*)(smB + r * 64 + c * 8), 16, 0, 0);
  }
  __syncthreads();

  const int lr = lane & 15, kq = lane >> 4;
  f32x4 acc[4][4] = {};
#pragma unroll
  for (int kk = 0; kk < 2; ++kk) {
    const int ch = (kk * 4 + kq) ^ (lr & 7);
    f16x8 av[4], bv[4];
#pragma unroll
    for (int i = 0; i < 4; ++i)
      av[i] = *reinterpret_cast<const f16x8*>(&smA[(wr * 64 + i * 16 + lr) * 64 + ch * 8]);
#pragma unroll
    for (int j = 0; j < 4; ++j)
      bv[j] = *reinterpret_cast<const f16x8*>(&smB[(wc * 64 + j * 16 + lr) * 64 + ch * 8]);
#pragma unroll
    for (int i = 0; i < 4; ++i)
#pragma unroll
      for (int j = 0; j < 4; ++j)
        acc[i][j] = __builtin_amdgcn_mfma_f32_16x16x32_f16(av[i], bv[j], acc[i][j], 0, 0, 0);
  }
  __syncthreads();

#pragma unroll
  for (int i = 0; i < 4; ++i) {
    int n0 = wr * 64 + i * 16 + kq * 4;
#pragma unroll
    for (int j = 0; j < 4; ++j) {
      int m = wc * 64 + j * 16 + lr;
      ushort4 o4;
      o4.x = f2h_bits(acc[i][j][0]); o4.y = f2h_bits(acc[i][j][1]);
      o4.z = f2h_bits(acc[i][j][2]); o4.w = f2h_bits(acc[i][j][3]);
      *reinterpret_cast<ushort4*>(Dt + m * NP + n0) = o4;
    }
  }
  __syncthreads();

  const int w2i = tid >> 7;
  const int b_  = (tid >> 4) & 7;
  const int a_  = (tid >> 2) & 3;
  const int w1q = (tid & 3) * 8;
  const int cch = (bx * 4 + a_) * 32 + (by * 8 + b_);
  const float u0 = wc1[2 * cch], u1 = wc1[2 * cch + 1];
  const float v0 = wc2[2 * cch], v1 = wc2[2 * cch + 1];
  const int cblk = (bx * 4 + by) * 32;
  __half* ACi = AC + ((size_t)img << 20);
  const int w1o = (tid >> 2) & 31, ck = tid & 3;

  for (int pass = 0; pass < 8; ++pass) {
    const int w2 = pass * 4 + w2i;
    const int w2n = (w2 < 31) ? w2 + 1 : 30;
    const __half* r0 = Dt + (b_ * 32 + w2) * NP + a_ * 32 + w1q;
    const __half* r1 = Dt + (b_ * 32 + w2n) * NP + a_ * 32 + w1q;
    float X[9];
    {
      ushort4 x0a = *reinterpret_cast<const ushort4*>(r0);
      ushort4 x0b = *reinterpret_cast<const ushort4*>(r0 + 4);
      ushort4 x1a = *reinterpret_cast<const ushort4*>(r1);
      ushort4 x1b = *reinterpret_cast<const ushort4*>(r1 + 4);
      X[0] = u0 * h2f_bits(x0a.x) + u1 * h2f_bits(x1a.x);
      X[1] = u0 * h2f_bits(x0a.y) + u1 * h2f_bits(x1a.y);
      X[2] = u0 * h2f_bits(x0a.z) + u1 * h2f_bits(x1a.z);
      X[3] = u0 * h2f_bits(x0a.w) + u1 * h2f_bits(x1a.w);
      X[4] = u0 * h2f_bits(x0b.x) + u1 * h2f_bits(x1b.x);
      X[5] = u0 * h2f_bits(x0b.y) + u1 * h2f_bits(x1b.y);
      X[6] = u0 * h2f_bits(x0b.z) + u1 * h2f_bits(x1b.z);
      X[7] = u0 * h2f_bits(x0b.w) + u1 * h2f_bits(x1b.w);
      X[8] = u0 * __half2float(r0[8]) + u1 * __half2float(r1[8]);
    }
#pragma unroll
    for (int k = 0; k < 8; ++k) {
      float ov = (w1q + k < 31) ? (v0 * X[k] + v1 * X[k + 1])
                                : (v0 * X[7] + v1 * X[6]);
      T[(w2i * 32 + w1q + k) * 40 + a_ * 8 + b_] = __float2half(ov);
    }
    __syncthreads();
    {
      const int w2o = pass * 4 + (tid >> 7);
      u16x8 v = *reinterpret_cast<const u16x8*>(T + ((tid >> 7) * 32 + w1o) * 40 + ck * 8);
      *reinterpret_cast<u16x8*>(ACi + (size_t)(w1o * 32 + w2o) * 1024 + cblk + ck * 8) = v;
    }
    __syncthreads();
  }
}

// ---------------- 256x128-tile 8-wave GEMM: 1x1 conv + BN + SiLU + softmax + PV ----------------
__global__ __launch_bounds__(512, 4) void gemm1x1pv(
    const __half* __restrict__ A,
    const __half* __restrict__ B, long long bStride,
    const __half* __restrict__ Vt,
    int K,
    const float* __restrict__ g, const float* __restrict__ b,
    const float* __restrict__ m, const float* __restrict__ vv,
    __half* __restrict__ O) {
  __shared__ __align__(16) char LDSRAW[81920];
  __half* smA = (__half*)LDSRAW;                 // [2][256*32] = 32KB
  __half* smB = (__half*)(LDSRAW + 32768);       // [2][128*32] = 16KB
  __half* Plds = (__half*)LDSRAW;                // [32][1024]  = 64KB (aliases stage)
  __half* Vlds = (__half*)(LDSRAW + 65536);      // [64][128]   = 16KB
  const int tid = threadIdx.x;
  const int lane = tid & 63, wid = tid >> 6;
  const int wr = wid >> 1, wc = wid & 1;         // 4 x 2 waves; wave tile 64x64
  const int gx = gridDim.x, gxy = gx * gridDim.y;
  const int nwg = gxy * gridDim.z;
  const int b_lin = blockIdx.x + blockIdx.y * gx + blockIdx.z * gxy;
  const int logical = (b_lin & 7) * (nwg >> 3) + (b_lin >> 3);
  const int bx = logical % gx, by = (logical / gx) % gridDim.y, bz = logical / gxy;
  const int img = bz, row0 = bx * 256, col0 = by * 128;
  const __half* Ab = A;
  const __half* Bb = B + (size_t)((long long)img * bStride);
  const __half* Vti = Vt + ((size_t)img << 16);

  const __half* pA[2]; int dA[2];
#pragma unroll
  for (int it = 0; it < 2; ++it) {
    int e = it * 512 + tid, r = e >> 2, c = e & 3, sc = c ^ ((r >> 1) & 3);
    pA[it] = Ab + (size_t)(row0 + r) * K + sc * 8;
    dA[it] = r * 32 + c * 8;
  }
  const __half* pB1; int dB1;
  {
    int r = tid >> 2, c = tid & 3, sc = c ^ ((r >> 1) & 3);
    pB1 = Bb + (size_t)(col0 + r) * K + sc * 8;
    dB1 = r * 32 + c * 8;
  }
  auto stage = [&](int buf, int kt) {
#pragma unroll
    for (int it = 0; it < 2; ++it)
      __builtin_amdgcn_global_load_lds(
          (const __attribute__((address_space(1))) unsigned int*)(pA[it] + kt),
          (__attribute__((address_space(3))) unsigned int*)(&smA[buf * 8192 + dA[it]]),
          16, 0, 0);
    __builtin_amdgcn_global_load_lds(
        (const __attribute__((address_space(1))) unsigned int*)(pB1 + kt),
        (__attribute__((address_space(3))) unsigned int*)(&smB[buf * 4096 + dB1]),
        16, 0, 0);
  };
  auto stageV = [&](int ph) {
#pragma unroll
    for (int it = 0; it < 2; ++it) {
      int c = it * 512 + tid;
      int d = c >> 4, col8 = c & 15;
      __builtin_amdgcn_global_load_lds(
          (const __attribute__((address_space(1))) unsigned int*)(Vti + (size_t)d * 1024 + ph * 128 + ((col8 ^ (d & 7)) * 8)),
          (__attribute__((address_space(3))) unsigned int*)(Vlds + c * 8),
          16, 0, 0);
    }
  };

  const int lr = lane & 15, kq = lane >> 4;
  const int ch = kq ^ ((lr >> 1) & 3);
  const int aOff = (wr * 64 + lr) * 32 + ch * 8;
  const int bOff = (wc * 64 + lr) * 32 + ch * 8;
  f32x4 acc[4][4] = {};

  const int NT = K / 32;
  stage(0, 0);
  __syncthreads();
  int cur = 0;
  for (int t = 0; t < NT; ++t) {
    f16x8 av[4], bv[4];
#pragma unroll
    for (int i = 0; i < 4; ++i)
      av[i] = *reinterpret_cast<const f16x8*>(&smA[cur * 8192 + aOff + i * 512]);
#pragma unroll
    for (int j = 0; j < 4; ++j)
      bv[j] = *reinterpret_cast<const f16x8*>(&smB[cur * 4096 + bOff + j * 512]);
    if (t + 1 < NT) stage(cur ^ 1, (t + 1) * 32);
    __builtin_amdgcn_s_setprio(1);
#pragma unroll
    for (int i = 0; i < 4; ++i)
#pragma unroll
      for (int j = 0; j < 4; ++j)
        acc[i][j] = __builtin_amdgcn_mfma_f32_16x16x32_f16(av[i], bv[j], acc[i][j], 0, 0, 0);
    __builtin_amdgcn_s_setprio(0);
    __syncthreads();
    cur ^= 1;
  }
  stageV(0);   // V phase-0: L2 latency hides under softmax
  const int ob = row0 + wr * 64;
#pragma unroll
  for (int ih = 0; ih < 2; ++ih) {
#pragma unroll
    for (int sh = 0; sh < 2; ++sh) {
      float v[2][2][4];
      float mx = -1e30f;
#pragma unroll
      for (int di = 0; di < 2; ++di) {
        int i = ih * 2 + di;
#pragma unroll
        for (int q = 0; q < 4; ++q) {
          int o = ob + i * 16 + kq * 4 + q;
          float sc = rsqrtf(vv[o] + 1e-5f) * g[o];
          float mo = m[o], bo = b[o];
#pragma unroll
          for (int dj = 0; dj < 2; ++dj) {
            float t = (acc[i][sh * 2 + dj][q] - mo) * sc + bo;
            t = t / (1.f + __expf(-t));       // SiLU
            v[di][dj][q] = t;
            mx = fmaxf(mx, t);
          }
        }
      }
#pragma unroll
      for (int off = 32; off; off >>= 1) mx = fmaxf(mx, __shfl_xor(mx, off));
      float sm = 0.f;
#pragma unroll
      for (int di = 0; di < 2; ++di)
#pragma unroll
        for (int dj = 0; dj < 2; ++dj)
#pragma unroll
          for (int q = 0; q < 4; ++q) {
            float e = __expf(v[di][dj][q] - mx);
            v[di][dj][q] = e; sm += e;
          }
#pragma unroll
      for (int off = 32; off; off >>= 1) sm += __shfl_xor(sm, off);
      float inv = 1.f / sm;
      const int ri = (wr * 2 + ih) * 4 + wc * 2 + sh;      // P row 0..31
      __half* Prow = Plds + ri * 1024;
      // address-chunk swizzle: mm ^ ((mm>>7)&7)<<4  -> kq groups on disjoint banks
#pragma unroll
      for (int di = 0; di < 2; ++di)
#pragma unroll
        for (int q = 0; q < 4; ++q) {
          int r32 = di * 16 + kq * 4 + q;
          int cx = (r32 >> 2) << 4;           // chunk XOR (same for both dj)
          int base = r32 * 32;
#pragma unroll
          for (int dj = 0; dj < 2; ++dj) {
            int mm = base + dj * 16 + lr;
            Prow[mm ^ cx] = __float2half(v[di][dj][q] * inv);
          }
        }
    }
  }
  __syncthreads();
  {
    const int rt = wid >> 2, dt = wid & 3;
    const int arow = rt * 16 + lr;
    const int d = dt * 16 + lr;
    const __half* Pr = Plds + arow * 1024;
    const __half* Vr = Vlds + d * 128;
    f32x4 acc2 = {};
    for (int ph = 0; ph < 8; ++ph) {
      const int pcx = ph << 4;                // read-side chunk XOR ((m0>>7)&7 == ph)
#pragma unroll
      for (int kk2 = 0; kk2 < 4; ++kk2) {
        int m0 = ph * 128 + kk2 * 32 + kq * 8;
        f16x8 a = *reinterpret_cast<const f16x8*>(&Pr[m0 ^ pcx]);
        f16x8 bb = *reinterpret_cast<const f16x8*>(&Vr[((kk2 * 4 + kq) ^ (d & 7)) * 8]);
        acc2 = __builtin_amdgcn_mfma_f32_16x16x32_f16(a, bb, acc2, 0, 0, 0);
      }
      if (ph < 7) {
        __syncthreads();
        stageV(ph + 1);
        __syncthreads();
      }
    }
#pragma unroll
    for (int q = 0; q < 4; ++q) {
      int ri = rt * 16 + kq * 4 + q;
      int n = (bx * 8 + (ri >> 2)) * 32 + by * 4 + (ri & 3);
      int dd = dt * 16 + lr;
      O[((size_t)((img >> 3) * 1024 + n)) * 512 + (img & 7) * 64 + dd] = __float2half(acc2[q]);
    }
  }
}

extern "C" void kernel_launch(void* const* d_in, const int* in_sizes, int n_in,
                              void* d_out, int out_size, void* d_ws, size_t ws_size,
                              hipStream_t stream) {
  const float* x     = (const float*)d_in[0];
  const float* ln_g  = (const float*)d_in[1];
  const float* ln_b  = (const float*)d_in[2];
  const float* w_qkv = (const float*)d_in[3];
  const float* wc1   = (const float*)d_in[4];
  const float* wc2   = (const float*)d_in[5];
  const float* w1x1  = (const float*)d_in[6];
  const float* bn_g  = (const float*)d_in[7];
  const float* bn_b  = (const float*)d_in[8];
  const float* bn_m  = (const float*)d_in[9];
  const float* bn_v  = (const float*)d_in[10];
  const float* w_out = (const float*)d_in[11];
  const float* b_out = (const float*)d_in[12];
  float* out = (float*)d_out;

  const size_t MB = 1024 * 1024;
  char* ws = (char*)d_ws;
  __half* ACb = (__half*)(ws + 64 * MB);      // region1 (64MB): AC (permuted channels)
  char* p = ws + 128 * MB;
  __half* XN    = (__half*)p; p += 2 * MB;            // 4096x256
  __half* WQKVT = (__half*)p; p += 1536 * 256 * 2;    // 1536x256
  __half* W1X1H = (__half*)p; p += 2 * MB;            // 1024x1024 (K permuted)
  __half* WOTT  = (__half*)p; p += 256 * 512 * 2;     // 256x512
  __half* Qb    = (__half*)p; p += 4 * MB;            // 32x1024x64 (scaled)
  __half* Kb    = (__half*)p; p += 4 * MB;            // 32x1024x64
  __half* Vtb   = (__half*)p; p += 4 * MB;            // 32x64x1024
  __half* Ob    = (__half*)p; p += 4 * MB;            // 4096x512

  prep_kernel<<<1024, 256, 0, stream>>>(w1x1, W1X1H);
  tcast_kernel<<<dim3(4, 24), 256, 0, stream>>>(w_qkv, WQKVT, 256, 1536);
  tcast_kernel<<<dim3(8, 4), 256, 0, stream>>>(w_out, WOTT, 512, 256);
  ln_kernel<<<4096, 256, 0, stream>>>(x, ln_g, ln_b, XN);

  gemm_qkv<<<dim3(32, 12), 256, 0, stream>>>(XN, WQKVT, Qb, Kb, Vtb);

  qkconv_kernel<<<dim3(8, 4, 32), 512, 0, stream>>>(Qb, Kb, wc1, wc2, ACb);

  gemm1x1pv<<<dim3(4, 8, 32), 512, 0, stream>>>(
      W1X1H, ACb, 1 << 20, Vtb, 1024, bn_g, bn_b, bn_m, bn_v, Ob);

  { EpiOut e{out, b_out};
    gemm_bt<64, 64, 64, 2, 2, 2, EpiOut><<<dim3(64, 4, 1), 256, 0, stream>>>(
        Ob, 0, WOTT, 0, 512, e); }
}

// Round 16
// 172.891 us; speedup vs baseline: 1.0279x; 1.0279x over previous
//
#include <hip/hip_runtime.h>
#include <hip/hip_fp16.h>

// AttentionQV0: LN -> QKV -> [QK^T + dw-convs fused] -> [1x1+BN+SiLU+softmax+PV fused] -> out proj
// B=2,P=2,N=1024,DIM=256,HEADS=8,DH=64,HW=32,C=1024. 32 "images" of 1024x1024 scores.
// D never hits HBM (conv in QK epilogue); P never hits HBM (PV in 1x1 epilogue).
// P LDS swizzle composes TWO involutions: chunk term ((mm>>7)<<4) makes the 4 kq
// write-groups conflict-free; row term ((row&7)<<3) spreads PV's per-lane row reads.
// AC uses a permuted channel axis c' = (bx*4+by)*32 + a*8 + b; W1X1H K-permuted to match.

#define DEV __device__ __forceinline__

typedef __attribute__((ext_vector_type(8))) _Float16 f16x8;
typedef __attribute__((ext_vector_type(4))) float f32x4;
typedef __attribute__((ext_vector_type(8))) unsigned short u16x8;

DEV float h2f_bits(unsigned short u) { __half h; *reinterpret_cast<unsigned short*>(&h) = u; return __half2float(h); }
DEV unsigned short f2h_bits(float f) { __half h = __float2half(f); return *reinterpret_cast<unsigned short*>(&h); }

// ---------------- prep: W1X1 permuted cast only ----------------
__global__ __launch_bounds__(256) void prep_kernel(
    const float* __restrict__ w1x1, __half* __restrict__ W1X1H) {
  int i0 = blockIdx.x * 256 + threadIdx.x;
  int stride = gridDim.x * 256;
  for (int i = i0; i < 1024 * 1024; i += stride) {         // permuted K axis: col p -> c(p)
    int o = i >> 10, p = i & 1023;
    int blk = p >> 5, r = p & 31, a = r >> 3, bb = r & 7;
    int h1 = (blk >> 2) * 4 + a, h2 = (blk & 3) * 8 + bb;
    W1X1H[i] = __float2half(w1x1[o * 1024 + h1 * 32 + h2]);
  }
}

// ---------------- transpose-cast: dst[c][r] f16 = src[r][c] f32, 64x64 LDS tiles ----------------
__global__ __launch_bounds__(256) void tcast_kernel(const float* __restrict__ src,
    __half* __restrict__ dst, int R, int C) {
  __shared__ __half T[64][80];                 // row stride 160B (16B-aligned)
  const int r0 = blockIdx.x * 64, c0 = blockIdx.y * 64;
  {
    int rr = threadIdx.x >> 2, cq = (threadIdx.x & 3) * 16;
    const float4* s = reinterpret_cast<const float4*>(src + (size_t)(r0 + rr) * C + c0 + cq);
#pragma unroll
    for (int u = 0; u < 4; ++u) {
      float4 f = s[u];
      T[cq + u * 4 + 0][rr] = __float2half(f.x);
      T[cq + u * 4 + 1][rr] = __float2half(f.y);
      T[cq + u * 4 + 2][rr] = __float2half(f.z);
      T[cq + u * 4 + 3][rr] = __float2half(f.w);
    }
  }
  __syncthreads();
  {
    int cc = threadIdx.x >> 2, rq = (threadIdx.x & 3) * 16;
    __half* d = dst + (size_t)(c0 + cc) * R + r0 + rq;
    *reinterpret_cast<u16x8*>(d)     = *reinterpret_cast<const u16x8*>(&T[cc][rq]);
    *reinterpret_cast<u16x8*>(d + 8) = *reinterpret_cast<const u16x8*>(&T[cc][rq + 8]);
  }
}

// ---------------- LayerNorm (row = token, 256 threads) ----------------
__global__ __launch_bounds__(256) void ln_kernel(const float* __restrict__ x,
    const float* __restrict__ g, const float* __restrict__ b, __half* __restrict__ XN) {
  int row = blockIdx.x;
  int tid = threadIdx.x, lane = tid & 63, wid = tid >> 6;
  float xv = x[(size_t)row * 256 + tid];
  float s = xv, q = xv * xv;
#pragma unroll
  for (int off = 32; off; off >>= 1) { s += __shfl_xor(s, off); q += __shfl_xor(q, off); }
  __shared__ float rs[4], rq[4];
  if (lane == 0) { rs[wid] = s; rq[wid] = q; }
  __syncthreads();
  s = rs[0] + rs[1] + rs[2] + rs[3];
  q = rq[0] + rq[1] + rq[2] + rq[3];
  float mu = s * (1.f / 256.f);
  float var = q * (1.f / 256.f) - mu * mu;
  float r = rsqrtf(var + 1e-5f);
  XN[(size_t)row * 256 + tid] = __float2half((xv - mu) * r * g[tid] + b[tid]);
}

// ---------------- QKV GEMM (dedicated): 128x128, BK=64, 4 waves ----------------
__global__ __launch_bounds__(256) void gemm_qkv(
    const __half* __restrict__ A, const __half* __restrict__ B,
    __half* __restrict__ Q, __half* __restrict__ Ko, __half* __restrict__ Vt) {
  constexpr int BK = 64, K = 256;
  __shared__ __align__(16) char RAW[65536];
  __half* smA = (__half*)RAW;                  // [2][128*64] 32KB
  __half* smB = (__half*)(RAW + 32768);        // [2][128*64] 32KB
  __half* Tld = (__half*)RAW;                  // [128][136] 34.8KB (epilogue alias)
  const int tid = threadIdx.x;
  const int lane = tid & 63, wid = tid >> 6;
  const int wr = wid >> 1, wc = wid & 1;
  const int gx = gridDim.x;
  const int nwg = gx * gridDim.y;
  const int b_lin = blockIdx.x + blockIdx.y * gx;
  const int logical = (b_lin & 7) * (nwg >> 3) + (b_lin >> 3);
  const int bx = logical % gx, by = logical / gx;
  const int row0 = bx * 128, col0 = by * 128;
  f32x4 acc[4][4] = {};
  const int lr = lane & 15;
  const int kq = lane >> 4;

  const __half* pA[4]; int dA[4];
  const __half* pB[4]; int dB[4];
#pragma unroll
  for (int it = 0; it < 4; ++it) {
    int e = it * 256 + tid, r = e >> 3, c = e & 7, sc = c ^ (r & 7);
    pA[it] = A + (size_t)(row0 + r) * K + sc * 8;
    pB[it] = B + (size_t)(col0 + r) * K + sc * 8;
    dA[it] = dB[it] = r * BK + c * 8;
  }
  auto stage = [&](int buf, int kt) {
#pragma unroll
    for (int it = 0; it < 4; ++it)
      __builtin_amdgcn_global_load_lds(
          (const __attribute__((address_space(1))) unsigned int*)(pA[it] + kt),
          (__attribute__((address_space(3))) unsigned int*)(&smA[buf * 8192 + dA[it]]),
          16, 0, 0);
#pragma unroll
    for (int it = 0; it < 4; ++it)
      __builtin_amdgcn_global_load_lds(
          (const __attribute__((address_space(1))) unsigned int*)(pB[it] + kt),
          (__attribute__((address_space(3))) unsigned int*)(&smB[buf * 8192 + dB[it]]),
          16, 0, 0);
  };

  const int NT = K / BK;                       // 4
  stage(0, 0);
  __syncthreads();
  int cur = 0;
  for (int t = 0; t < NT; ++t) {
    if (t + 1 < NT) stage(cur ^ 1, (t + 1) * BK);
#pragma unroll
    for (int kk = 0; kk < 2; ++kk) {
      f16x8 av[4], bv[4];
#pragma unroll
      for (int i = 0; i < 4; ++i) {
        int row = wr * 64 + i * 16 + lr;
        int ch = (kk * 4 + kq) ^ (lr & 7);
        av[i] = *reinterpret_cast<const f16x8*>(&smA[cur * 8192 + row * BK + ch * 8]);
      }
#pragma unroll
      for (int j = 0; j < 4; ++j) {
        int row = wc * 64 + j * 16 + lr;
        int ch = (kk * 4 + kq) ^ (lr & 7);
        bv[j] = *reinterpret_cast<const f16x8*>(&smB[cur * 8192 + row * BK + ch * 8]);
      }
#pragma unroll
      for (int i = 0; i < 4; ++i)
#pragma unroll
        for (int j = 0; j < 4; ++j)
          acc[i][j] = __builtin_amdgcn_mfma_f32_16x16x32_f16(av[i], bv[j], acc[i][j], 0, 0, 0);
    }
    __syncthreads();
    cur ^= 1;
  }

  const int bp = row0 >> 10, n0 = row0 & 1023;
  if (by < 8) {
#pragma unroll
    for (int i = 0; i < 4; ++i)
#pragma unroll
      for (int j = 0; j < 4; ++j)
#pragma unroll
        for (int q = 0; q < 4; ++q) {
          int t = row0 + wr * 64 + i * 16 + kq * 4 + q;
          int jj = col0 + wc * 64 + j * 16 + lr;
          int part = jj >> 9, inner = jj & 511;
          int h = inner >> 6, d = inner & 63;
          int n = t & 1023;
          size_t img = (size_t)((t >> 10) * 8 + h);
          float v = acc[i][j][q];
          if (part == 0) Q[(img * 1024 + n) * 64 + d] = __float2half(v * 0.125f);
          else           Ko[(img * 1024 + n) * 64 + d] = __float2half(v);
        }
  } else {
#pragma unroll
    for (int i = 0; i < 4; ++i)
#pragma unroll
      for (int j = 0; j < 4; ++j)
#pragma unroll
        for (int q = 0; q < 4; ++q) {
          int nl = wr * 64 + i * 16 + kq * 4 + q;
          int jl = wc * 64 + j * 16 + lr;
          int ch = (nl >> 3) ^ (jl & 7);
          Tld[jl * 136 + ch * 8 + (nl & 7)] = __float2half(acc[i][j][q]);
        }
    __syncthreads();
    const int jl = tid >> 1, hf = tid & 1;
    const int d = jl & 63;
    const int vimg = bp * 8 + (by - 8) * 2 + (jl >> 6);
    __half* dst = Vt + ((size_t)(vimg * 64 + d)) * 1024 + n0 + hf * 64;
#pragma unroll
    for (int u = 0; u < 8; ++u) {
      int cidx = (hf * 8 + u) ^ (jl & 7);
      *reinterpret_cast<u16x8*>(dst + u * 8) =
          *reinterpret_cast<const u16x8*>(Tld + jl * 136 + cidx * 8);
    }
  }
}

// ---------------- out-proj GEMM (generic BT, 4 waves) ----------------
struct EpiOut {
  float* out; const float* bias;
  DEV void store(int, int t, int j, float v) const {
    out[(size_t)t * 256 + j] = v + bias[j];
  }
};

template <int BM, int BN, int BK, int WGN, int FM, int FN, class Epi>
__global__ __launch_bounds__(256) void gemm_bt(
    const __half* __restrict__ A, long long aStride,
    const __half* __restrict__ B, long long bStride,
    int K, Epi epi) {
  constexpr int CPR = BK / 8;
  constexpr int NCA = (BM * BK) / (8 * 256);
  constexpr int NCB = (BN * BK) / (8 * 256);
  constexpr int KSUB = BK / 32;
  __shared__ __align__(16) __half smA[2][BM * BK];
  __shared__ __align__(16) __half smB[2][BN * BK];
  const int tid = threadIdx.x;
  const int lane = tid & 63, wid = tid >> 6;
  const int wr = wid / WGN, wc = wid % WGN;
  const int gx = gridDim.x, gxy = gridDim.x * gridDim.y;
  const int nwg = gxy * gridDim.z;
  const int b_lin = blockIdx.x + blockIdx.y * gx + blockIdx.z * gxy;
  const int logical = (b_lin & 7) * (nwg >> 3) + (b_lin >> 3);
  const int bx = logical % gx, by = (logical / gx) % gridDim.y, bz = logical / gxy;
  const int img = bz;
  const int row0 = bx * BM;
  const int col0 = by * BN;
  const __half* Ab = A + (size_t)((long long)img * aStride);
  const __half* Bb = B + (size_t)((long long)img * bStride);
  f32x4 acc[FM][FN] = {};
  const int lr = lane & 15;
  const int kq = lane >> 4;

  auto swz = [](int c, int r) -> int {
    return (CPR == 8) ? (c ^ (r & 7)) : (c ^ ((r >> 1) & 3));
  };

  const __half* pA[NCA]; int dA[NCA];
  const __half* pB[NCB]; int dB[NCB];
#pragma unroll
  for (int it = 0; it < NCA; ++it) {
    int e = it * 256 + tid, r = e / CPR, c = e % CPR;
    pA[it] = Ab + (size_t)(row0 + r) * K + swz(c, r) * 8;
    dA[it] = r * BK + c * 8;
  }
#pragma unroll
  for (int it = 0; it < NCB; ++it) {
    int e = it * 256 + tid, r = e / CPR, c = e % CPR;
    pB[it] = Bb + (size_t)(col0 + r) * K + swz(c, r) * 8;
    dB[it] = r * BK + c * 8;
  }

  auto stage = [&](int buf, int kt) {
#pragma unroll
    for (int it = 0; it < NCA; ++it)
      __builtin_amdgcn_global_load_lds(
          (const __attribute__((address_space(1))) unsigned int*)(pA[it] + kt),
          (__attribute__((address_space(3))) unsigned int*)(&smA[buf][dA[it]]),
          16, 0, 0);
#pragma unroll
    for (int it = 0; it < NCB; ++it)
      __builtin_amdgcn_global_load_lds(
          (const __attribute__((address_space(1))) unsigned int*)(pB[it] + kt),
          (__attribute__((address_space(3))) unsigned int*)(&smB[buf][dB[it]]),
          16, 0, 0);
  };

  const int NT = K / BK;
  stage(0, 0);
  __syncthreads();
  int cur = 0;
  for (int t = 0; t < NT; ++t) {
    if (t + 1 < NT) stage(cur ^ 1, (t + 1) * BK);
#pragma unroll
    for (int kk = 0; kk < KSUB; ++kk) {
      f16x8 av[FM], bv[FN];
#pragma unroll
      for (int i = 0; i < FM; ++i) {
        int row = wr * FM * 16 + i * 16 + lr;
        int ch = swz(kk * 4 + kq, lr);
        av[i] = *reinterpret_cast<const f16x8*>(&smA[cur][row * BK + ch * 8]);
      }
#pragma unroll
      for (int j = 0; j < FN; ++j) {
        int row = wc * FN * 16 + j * 16 + lr;
        int ch = swz(kk * 4 + kq, lr);
        bv[j] = *reinterpret_cast<const f16x8*>(&smB[cur][row * BK + ch * 8]);
      }
#pragma unroll
      for (int i = 0; i < FM; ++i)
#pragma unroll
        for (int j = 0; j < FN; ++j)
          acc[i][j] = __builtin_amdgcn_mfma_f32_16x16x32_f16(av[i], bv[j], acc[i][j], 0, 0, 0);
    }
    __syncthreads();
    cur ^= 1;
  }

  const int orow = row0 + wr * FM * 16 + (lane >> 4) * 4;
  const int ocol = col0 + wc * FN * 16 + lr;
#pragma unroll
  for (int i = 0; i < FM; ++i)
#pragma unroll
    for (int j = 0; j < FN; ++j)
#pragma unroll
      for (int q = 0; q < 4; ++q)
        epi.store(img, orow + i * 16 + q, ocol + j * 16, acc[i][j][q]);
}

// ---------------- fused QK^T + depthwise convs ----------------
__global__ __launch_bounds__(512) void qkconv_kernel(
    const __half* __restrict__ Q, const __half* __restrict__ Km,
    const float* __restrict__ wc1, const float* __restrict__ wc2,
    __half* __restrict__ AC) {
  constexpr int NP = 132;                       // Dt inner pad (halfs)
  __shared__ __align__(16) char LDS[77824];     // max(stage 48K, Dt 66K) + T 10K
  __half* smA = (__half*)LDS;                   // [128][64]  16384 B
  __half* smB = (__half*)(LDS + 16384);         // [256][64]  32768 B
  __half* Dt  = (__half*)LDS;                   // [256][132] 67584 B (aliases stage)
  __half* T   = (__half*)(LDS + 67584);         // [4][32][40] 10240 B
  const int tid = threadIdx.x;
  const int lane = tid & 63, wid = tid >> 6;
  const int wr = wid >> 2, wc = wid & 3;
  const int gx = gridDim.x, gxy = gx * gridDim.y;
  const int nwg = gxy * gridDim.z;
  const int b_lin = blockIdx.x + blockIdx.y * gx + blockIdx.z * gxy;
  const int logical = (b_lin & 7) * (nwg >> 3) + (b_lin >> 3);
  const int bx = logical % gx, by = (logical / gx) % gridDim.y, bz = logical / gxy;
  const int img = bz, row0 = bx * 128, col0 = by * 256;
  const __half* Qi = Q + ((size_t)img << 16);
  const __half* Ki = Km + ((size_t)img << 16);

#pragma unroll
  for (int it = 0; it < 2; ++it) {
    int e = it * 512 + tid, r = e >> 3, c = e & 7, sc = c ^ (r & 7);
    __builtin_amdgcn_global_load_lds(
        (const __attribute__((address_space(1))) unsigned int*)(Qi + (size_t)(row0 + r) * 64 + sc * 8),
        (__attribute__((address_space(3))) unsigned int*)(smA + r * 64 + c * 8), 16, 0, 0);
  }
#pragma unroll
  for (int it = 0; it < 4; ++it) {
    int e = it * 512 + tid, r = e >> 3, c = e & 7, sc = c ^ (r & 7);
    __builtin_amdgcn_global_load_lds(
        (const __attribute__((address_space(1))) unsigned int*)(Ki + (size_t)(col0 + r) * 64 + sc * 8),
        (__attribute__((address_space(3))) unsigned int*)(smB + r * 64 + c * 8), 16, 0, 0);
  }
  __syncthreads();

  const int lr = lane & 15, kq = lane >> 4;
  f32x4 acc[4][4] = {};
#pragma unroll
  for (int kk = 0; kk < 2; ++kk) {
    const int ch = (kk * 4 + kq) ^ (lr & 7);
    f16x8 av[4], bv[4];
#pragma unroll
    for (int i = 0; i < 4; ++i)
      av[i] = *reinterpret_cast<const f16x8*>(&smA[(wr * 64 + i * 16 + lr) * 64 + ch * 8]);
#pragma unroll
    for (int j = 0; j < 4; ++j)
      bv[j] = *reinterpret_cast<const f16x8*>(&smB[(wc * 64 + j * 16 + lr) * 64 + ch * 8]);
#pragma unroll
    for (int i = 0; i < 4; ++i)
#pragma unroll
      for (int j = 0; j < 4; ++j)
        acc[i][j] = __builtin_amdgcn_mfma_f32_16x16x32_f16(av[i], bv[j], acc[i][j], 0, 0, 0);
  }
  __syncthreads();

#pragma unroll
  for (int i = 0; i < 4; ++i) {
    int n0 = wr * 64 + i * 16 + kq * 4;
#pragma unroll
    for (int j = 0; j < 4; ++j) {
      int m = wc * 64 + j * 16 + lr;
      ushort4 o4;
      o4.x = f2h_bits(acc[i][j][0]); o4.y = f2h_bits(acc[i][j][1]);
      o4.z = f2h_bits(acc[i][j][2]); o4.w = f2h_bits(acc[i][j][3]);
      *reinterpret_cast<ushort4*>(Dt + m * NP + n0) = o4;
    }
  }
  __syncthreads();

  const int w2i = tid >> 7;
  const int b_  = (tid >> 4) & 7;
  const int a_  = (tid >> 2) & 3;
  const int w1q = (tid & 3) * 8;
  const int cch = (bx * 4 + a_) * 32 + (by * 8 + b_);
  const float u0 = wc1[2 * cch], u1 = wc1[2 * cch + 1];
  const float v0 = wc2[2 * cch], v1 = wc2[2 * cch + 1];
  const int cblk = (bx * 4 + by) * 32;
  __half* ACi = AC + ((size_t)img << 20);
  const int w1o = (tid >> 2) & 31, ck = tid & 3;

  for (int pass = 0; pass < 8; ++pass) {
    const int w2 = pass * 4 + w2i;
    const int w2n = (w2 < 31) ? w2 + 1 : 30;
    const __half* r0 = Dt + (b_ * 32 + w2) * NP + a_ * 32 + w1q;
    const __half* r1 = Dt + (b_ * 32 + w2n) * NP + a_ * 32 + w1q;
    float X[9];
    {
      ushort4 x0a = *reinterpret_cast<const ushort4*>(r0);
      ushort4 x0b = *reinterpret_cast<const ushort4*>(r0 + 4);
      ushort4 x1a = *reinterpret_cast<const ushort4*>(r1);
      ushort4 x1b = *reinterpret_cast<const ushort4*>(r1 + 4);
      X[0] = u0 * h2f_bits(x0a.x) + u1 * h2f_bits(x1a.x);
      X[1] = u0 * h2f_bits(x0a.y) + u1 * h2f_bits(x1a.y);
      X[2] = u0 * h2f_bits(x0a.z) + u1 * h2f_bits(x1a.z);
      X[3] = u0 * h2f_bits(x0a.w) + u1 * h2f_bits(x1a.w);
      X[4] = u0 * h2f_bits(x0b.x) + u1 * h2f_bits(x1b.x);
      X[5] = u0 * h2f_bits(x0b.y) + u1 * h2f_bits(x1b.y);
      X[6] = u0 * h2f_bits(x0b.z) + u1 * h2f_bits(x1b.z);
      X[7] = u0 * h2f_bits(x0b.w) + u1 * h2f_bits(x1b.w);
      X[8] = u0 * __half2float(r0[8]) + u1 * __half2float(r1[8]);
    }
#pragma unroll
    for (int k = 0; k < 8; ++k) {
      float ov = (w1q + k < 31) ? (v0 * X[k] + v1 * X[k + 1])
                                : (v0 * X[7] + v1 * X[6]);
      T[(w2i * 32 + w1q + k) * 40 + a_ * 8 + b_] = __float2half(ov);
    }
    __syncthreads();
    {
      const int w2o = pass * 4 + (tid >> 7);
      u16x8 v = *reinterpret_cast<const u16x8*>(T + ((tid >> 7) * 32 + w1o) * 40 + ck * 8);
      *reinterpret_cast<u16x8*>(ACi + (size_t)(w1o * 32 + w2o) * 1024 + cblk + ck * 8) = v;
    }
    __syncthreads();
  }
}

// ---------------- 256x128-tile 8-wave GEMM: 1x1 conv + BN + SiLU + softmax + PV ----------------
__global__ __launch_bounds__(512, 4) void gemm1x1pv(
    const __half* __restrict__ A,
    const __half* __restrict__ B, long long bStride,
    const __half* __restrict__ Vt,
    int K,
    const float* __restrict__ g, const float* __restrict__ b,
    const float* __restrict__ m, const float* __restrict__ vv,
    __half* __restrict__ O) {
  __shared__ __align__(16) char LDSRAW[81920];
  __half* smA = (__half*)LDSRAW;                 // [2][256*32] = 32KB
  __half* smB = (__half*)(LDSRAW + 32768);       // [2][128*32] = 16KB
  __half* Plds = (__half*)LDSRAW;                // [32][1024]  = 64KB (aliases stage)
  __half* Vlds = (__half*)(LDSRAW + 65536);      // [64][128]   = 16KB
  const int tid = threadIdx.x;
  const int lane = tid & 63, wid = tid >> 6;
  const int wr = wid >> 1, wc = wid & 1;         // 4 x 2 waves; wave tile 64x64
  const int gx = gridDim.x, gxy = gx * gridDim.y;
  const int nwg = gxy * gridDim.z;
  const int b_lin = blockIdx.x + blockIdx.y * gx + blockIdx.z * gxy;
  const int logical = (b_lin & 7) * (nwg >> 3) + (b_lin >> 3);
  const int bx = logical % gx, by = (logical / gx) % gridDim.y, bz = logical / gxy;
  const int img = bz, row0 = bx * 256, col0 = by * 128;
  const __half* Ab = A;
  const __half* Bb = B + (size_t)((long long)img * bStride);
  const __half* Vti = Vt + ((size_t)img << 16);

  const __half* pA[2]; int dA[2];
#pragma unroll
  for (int it = 0; it < 2; ++it) {
    int e = it * 512 + tid, r = e >> 2, c = e & 3, sc = c ^ ((r >> 1) & 3);
    pA[it] = Ab + (size_t)(row0 + r) * K + sc * 8;
    dA[it] = r * 32 + c * 8;
  }
  const __half* pB1; int dB1;
  {
    int r = tid >> 2, c = tid & 3, sc = c ^ ((r >> 1) & 3);
    pB1 = Bb + (size_t)(col0 + r) * K + sc * 8;
    dB1 = r * 32 + c * 8;
  }
  auto stage = [&](int buf, int kt) {
#pragma unroll
    for (int it = 0; it < 2; ++it)
      __builtin_amdgcn_global_load_lds(
          (const __attribute__((address_space(1))) unsigned int*)(pA[it] + kt),
          (__attribute__((address_space(3))) unsigned int*)(&smA[buf * 8192 + dA[it]]),
          16, 0, 0);
    __builtin_amdgcn_global_load_lds(
        (const __attribute__((address_space(1))) unsigned int*)(pB1 + kt),
        (__attribute__((address_space(3))) unsigned int*)(&smB[buf * 4096 + dB1]),
        16, 0, 0);
  };
  auto stageV = [&](int ph) {
#pragma unroll
    for (int it = 0; it < 2; ++it) {
      int c = it * 512 + tid;
      int d = c >> 4, col8 = c & 15;
      __builtin_amdgcn_global_load_lds(
          (const __attribute__((address_space(1))) unsigned int*)(Vti + (size_t)d * 1024 + ph * 128 + ((col8 ^ (d & 7)) * 8)),
          (__attribute__((address_space(3))) unsigned int*)(Vlds + c * 8),
          16, 0, 0);
    }
  };

  const int lr = lane & 15, kq = lane >> 4;
  const int ch = kq ^ ((lr >> 1) & 3);
  const int aOff = (wr * 64 + lr) * 32 + ch * 8;
  const int bOff = (wc * 64 + lr) * 32 + ch * 8;
  f32x4 acc[4][4] = {};

  const int NT = K / 32;
  stage(0, 0);
  __syncthreads();
  int cur = 0;
  for (int t = 0; t < NT; ++t) {
    if (t + 1 < NT) stage(cur ^ 1, (t + 1) * 32);
    f16x8 av[4], bv[4];
#pragma unroll
    for (int i = 0; i < 4; ++i)
      av[i] = *reinterpret_cast<const f16x8*>(&smA[cur * 8192 + aOff + i * 512]);
#pragma unroll
    for (int j = 0; j < 4; ++j)
      bv[j] = *reinterpret_cast<const f16x8*>(&smB[cur * 4096 + bOff + j * 512]);
    __builtin_amdgcn_s_setprio(1);
#pragma unroll
    for (int i = 0; i < 4; ++i)
#pragma unroll
      for (int j = 0; j < 4; ++j)
        acc[i][j] = __builtin_amdgcn_mfma_f32_16x16x32_f16(av[i], bv[j], acc[i][j], 0, 0, 0);
    __builtin_amdgcn_s_setprio(0);
    __syncthreads();
    cur ^= 1;
  }
  stageV(0);   // V phase-0: L2 latency hides under softmax
  const int ob = row0 + wr * 64;
#pragma unroll
  for (int ih = 0; ih < 2; ++ih) {
#pragma unroll
    for (int sh = 0; sh < 2; ++sh) {
      float v[2][2][4];
      float mx = -1e30f;
#pragma unroll
      for (int di = 0; di < 2; ++di) {
        int i = ih * 2 + di;
#pragma unroll
        for (int q = 0; q < 4; ++q) {
          int o = ob + i * 16 + kq * 4 + q;
          float sc = rsqrtf(vv[o] + 1e-5f) * g[o];
          float mo = m[o], bo = b[o];
#pragma unroll
          for (int dj = 0; dj < 2; ++dj) {
            float t = (acc[i][sh * 2 + dj][q] - mo) * sc + bo;
            t = t / (1.f + __expf(-t));       // SiLU
            v[di][dj][q] = t;
            mx = fmaxf(mx, t);
          }
        }
      }
#pragma unroll
      for (int off = 32; off; off >>= 1) mx = fmaxf(mx, __shfl_xor(mx, off));
      float sm = 0.f;
#pragma unroll
      for (int di = 0; di < 2; ++di)
#pragma unroll
        for (int dj = 0; dj < 2; ++dj)
#pragma unroll
          for (int q = 0; q < 4; ++q) {
            float e = __expf(v[di][dj][q] - mx);
            v[di][dj][q] = e; sm += e;
          }
#pragma unroll
      for (int off = 32; off; off >>= 1) sm += __shfl_xor(sm, off);
      float inv = 1.f / sm;
      const int ri = (wr * 2 + ih) * 4 + wc * 2 + sh;      // P row 0..31
      const int rsw = (ri & 7) << 3;                        // row involution
      __half* Prow = Plds + ri * 1024;
#pragma unroll
      for (int di = 0; di < 2; ++di)
#pragma unroll
        for (int q = 0; q < 4; ++q) {
          int r32 = di * 16 + kq * 4 + q;
          int cx = ((r32 >> 2) << 4) ^ rsw;   // chunk involution ^ row involution
          int base = r32 * 32;
#pragma unroll
          for (int dj = 0; dj < 2; ++dj) {
            int mm = base + dj * 16 + lr;
            Prow[mm ^ cx] = __float2half(v[di][dj][q] * inv);
          }
        }
    }
  }
  __syncthreads();
  {
    const int rt = wid >> 2, dt = wid & 3;
    const int arow = rt * 16 + lr;
    const int asw = (arow & 7) << 3;
    const int d = dt * 16 + lr;
    const __half* Pr = Plds + arow * 1024;
    const __half* Vr = Vlds + d * 128;
    f32x4 acc2 = {};
    for (int ph = 0; ph < 8; ++ph) {
      const int pcx = (ph << 4) ^ asw;        // read-side: chunk ^ row involutions
#pragma unroll
      for (int kk2 = 0; kk2 < 4; ++kk2) {
        int m0 = ph * 128 + kk2 * 32 + kq * 8;
        f16x8 a = *reinterpret_cast<const f16x8*>(&Pr[m0 ^ pcx]);
        f16x8 bb = *reinterpret_cast<const f16x8*>(&Vr[((kk2 * 4 + kq) ^ (d & 7)) * 8]);
        acc2 = __builtin_amdgcn_mfma_f32_16x16x32_f16(a, bb, acc2, 0, 0, 0);
      }
      if (ph < 7) {
        __syncthreads();
        stageV(ph + 1);
        __syncthreads();
      }
    }
#pragma unroll
    for (int q = 0; q < 4; ++q) {
      int ri = rt * 16 + kq * 4 + q;
      int n = (bx * 8 + (ri >> 2)) * 32 + by * 4 + (ri & 3);
      int dd = dt * 16 + lr;
      O[((size_t)((img >> 3) * 1024 + n)) * 512 + (img & 7) * 64 + dd] = __float2half(acc2[q]);
    }
  }
}

extern "C" void kernel_launch(void* const* d_in, const int* in_sizes, int n_in,
                              void* d_out, int out_size, void* d_ws, size_t ws_size,
                              hipStream_t stream) {
  const float* x     = (const float*)d_in[0];
  const float* ln_g  = (const float*)d_in[1];
  const float* ln_b  = (const float*)d_in[2];
  const float* w_qkv = (const float*)d_in[3];
  const float* wc1   = (const float*)d_in[4];
  const float* wc2   = (const float*)d_in[5];
  const float* w1x1  = (const float*)d_in[6];
  const float* bn_g  = (const float*)d_in[7];
  const float* bn_b  = (const float*)d_in[8];
  const float* bn_m  = (const float*)d_in[9];
  const float* bn_v  = (const float*)d_in[10];
  const float* w_out = (const float*)d_in[11];
  const float* b_out = (const float*)d_in[12];
  float* out = (float*)d_out;

  const size_t MB = 1024 * 1024;
  char* ws = (char*)d_ws;
  __half* ACb = (__half*)(ws + 64 * MB);      // region1 (64MB): AC (permuted channels)
  char* p = ws + 128 * MB;
  __half* XN    = (__half*)p; p += 2 * MB;            // 4096x256
  __half* WQKVT = (__half*)p; p += 1536 * 256 * 2;    // 1536x256
  __half* W1X1H = (__half*)p; p += 2 * MB;            // 1024x1024 (K permuted)
  __half* WOTT  = (__half*)p; p += 256 * 512 * 2;     // 256x512
  __half* Qb    = (__half*)p; p += 4 * MB;            // 32x1024x64 (scaled)
  __half* Kb    = (__half*)p; p += 4 * MB;            // 32x1024x64
  __half* Vtb   = (__half*)p; p += 4 * MB;            // 32x64x1024
  __half* Ob    = (__half*)p; p += 4 * MB;            // 4096x512

  prep_kernel<<<1024, 256, 0, stream>>>(w1x1, W1X1H);
  tcast_kernel<<<dim3(4, 24), 256, 0, stream>>>(w_qkv, WQKVT, 256, 1536);
  tcast_kernel<<<dim3(8, 4), 256, 0, stream>>>(w_out, WOTT, 512, 256);
  ln_kernel<<<4096, 256, 0, stream>>>(x, ln_g, ln_b, XN);

  gemm_qkv<<<dim3(32, 12), 256, 0, stream>>>(XN, WQKVT, Qb, Kb, Vtb);

  qkconv_kernel<<<dim3(8, 4, 32), 512, 0, stream>>>(Qb, Kb, wc1, wc2, ACb);

  gemm1x1pv<<<dim3(4, 8, 32), 512, 0, stream>>>(
      W1X1H, ACb, 1 << 20, Vtb, 1024, bn_g, bn_b, bn_m, bn_v, Ob);

  { EpiOut e{out, b_out};
    gemm_bt<64, 64, 64, 2, 2, 2, EpiOut><<<dim3(64, 4, 1), 256, 0, stream>>>(
        Ob, 0, WOTT, 0, 512, e); }
}

// Round 17
// 168.968 us; speedup vs baseline: 1.0518x; 1.0232x over previous
//
#include <hip/hip_runtime.h>
#include <hip/hip_fp16.h>

// AttentionQV0: LN -> QKV -> [QK^T + dw-convs fused] -> [1x1+BN+SiLU+softmax+PV fused] -> out proj
// B=2,P=2,N=1024,DIM=256,HEADS=8,DH=64,HW=32,C=1024. 32 "images" of 1024x1024 scores.
// D never hits HBM (conv in QK epilogue); P never hits HBM (PV in 1x1 epilogue).
// V written via LDS transpose (coalesced 128B runs); weight transposes via LDS tiles.
// P LDS uses row-XOR swizzle ((row&7)<<3): protects PV's per-lane-row reads (the
// critical path). Write-side conflicts (~3.1M) are hidden by the 2-phase regime —
// chunk-XOR variants (r15/r16) regressed net time. This is the best-measured config.
// AC uses a permuted channel axis c' = (bx*4+by)*32 + a*8 + b; W1X1H K-permuted to match.

#define DEV __device__ __forceinline__

typedef __attribute__((ext_vector_type(8))) _Float16 f16x8;
typedef __attribute__((ext_vector_type(4))) float f32x4;
typedef __attribute__((ext_vector_type(8))) unsigned short u16x8;

DEV float h2f_bits(unsigned short u) { __half h; *reinterpret_cast<unsigned short*>(&h) = u; return __half2float(h); }
DEV unsigned short f2h_bits(float f) { __half h = __float2half(f); return *reinterpret_cast<unsigned short*>(&h); }

// ---------------- prep: W1X1 permuted cast only ----------------
__global__ __launch_bounds__(256) void prep_kernel(
    const float* __restrict__ w1x1, __half* __restrict__ W1X1H) {
  int i0 = blockIdx.x * 256 + threadIdx.x;
  int stride = gridDim.x * 256;
  for (int i = i0; i < 1024 * 1024; i += stride) {         // permuted K axis: col p -> c(p)
    int o = i >> 10, p = i & 1023;
    int blk = p >> 5, r = p & 31, a = r >> 3, bb = r & 7;
    int h1 = (blk >> 2) * 4 + a, h2 = (blk & 3) * 8 + bb;
    W1X1H[i] = __float2half(w1x1[o * 1024 + h1 * 32 + h2]);
  }
}

// ---------------- transpose-cast: dst[c][r] f16 = src[r][c] f32, 64x64 LDS tiles ----------------
__global__ __launch_bounds__(256) void tcast_kernel(const float* __restrict__ src,
    __half* __restrict__ dst, int R, int C) {
  __shared__ __half T[64][80];                 // row stride 160B (16B-aligned)
  const int r0 = blockIdx.x * 64, c0 = blockIdx.y * 64;
  {
    int rr = threadIdx.x >> 2, cq = (threadIdx.x & 3) * 16;
    const float4* s = reinterpret_cast<const float4*>(src + (size_t)(r0 + rr) * C + c0 + cq);
#pragma unroll
    for (int u = 0; u < 4; ++u) {
      float4 f = s[u];
      T[cq + u * 4 + 0][rr] = __float2half(f.x);
      T[cq + u * 4 + 1][rr] = __float2half(f.y);
      T[cq + u * 4 + 2][rr] = __float2half(f.z);
      T[cq + u * 4 + 3][rr] = __float2half(f.w);
    }
  }
  __syncthreads();
  {
    int cc = threadIdx.x >> 2, rq = (threadIdx.x & 3) * 16;
    __half* d = dst + (size_t)(c0 + cc) * R + r0 + rq;
    *reinterpret_cast<u16x8*>(d)     = *reinterpret_cast<const u16x8*>(&T[cc][rq]);
    *reinterpret_cast<u16x8*>(d + 8) = *reinterpret_cast<const u16x8*>(&T[cc][rq + 8]);
  }
}

// ---------------- LayerNorm (row = token, 256 threads) ----------------
__global__ __launch_bounds__(256) void ln_kernel(const float* __restrict__ x,
    const float* __restrict__ g, const float* __restrict__ b, __half* __restrict__ XN) {
  int row = blockIdx.x;
  int tid = threadIdx.x, lane = tid & 63, wid = tid >> 6;
  float xv = x[(size_t)row * 256 + tid];
  float s = xv, q = xv * xv;
#pragma unroll
  for (int off = 32; off; off >>= 1) { s += __shfl_xor(s, off); q += __shfl_xor(q, off); }
  __shared__ float rs[4], rq[4];
  if (lane == 0) { rs[wid] = s; rq[wid] = q; }
  __syncthreads();
  s = rs[0] + rs[1] + rs[2] + rs[3];
  q = rq[0] + rq[1] + rq[2] + rq[3];
  float mu = s * (1.f / 256.f);
  float var = q * (1.f / 256.f) - mu * mu;
  float r = rsqrtf(var + 1e-5f);
  XN[(size_t)row * 256 + tid] = __float2half((xv - mu) * r * g[tid] + b[tid]);
}

// ---------------- QKV GEMM (dedicated): 128x128, BK=64, 4 waves ----------------
__global__ __launch_bounds__(256) void gemm_qkv(
    const __half* __restrict__ A, const __half* __restrict__ B,
    __half* __restrict__ Q, __half* __restrict__ Ko, __half* __restrict__ Vt) {
  constexpr int BK = 64, K = 256;
  __shared__ __align__(16) char RAW[65536];
  __half* smA = (__half*)RAW;                  // [2][128*64] 32KB
  __half* smB = (__half*)(RAW + 32768);        // [2][128*64] 32KB
  __half* Tld = (__half*)RAW;                  // [128][136] 34.8KB (epilogue alias)
  const int tid = threadIdx.x;
  const int lane = tid & 63, wid = tid >> 6;
  const int wr = wid >> 1, wc = wid & 1;
  const int gx = gridDim.x;
  const int nwg = gx * gridDim.y;
  const int b_lin = blockIdx.x + blockIdx.y * gx;
  const int logical = (b_lin & 7) * (nwg >> 3) + (b_lin >> 3);
  const int bx = logical % gx, by = logical / gx;
  const int row0 = bx * 128, col0 = by * 128;
  f32x4 acc[4][4] = {};
  const int lr = lane & 15;
  const int kq = lane >> 4;

  const __half* pA[4]; int dA[4];
  const __half* pB[4]; int dB[4];
#pragma unroll
  for (int it = 0; it < 4; ++it) {
    int e = it * 256 + tid, r = e >> 3, c = e & 7, sc = c ^ (r & 7);
    pA[it] = A + (size_t)(row0 + r) * K + sc * 8;
    pB[it] = B + (size_t)(col0 + r) * K + sc * 8;
    dA[it] = dB[it] = r * BK + c * 8;
  }
  auto stage = [&](int buf, int kt) {
#pragma unroll
    for (int it = 0; it < 4; ++it)
      __builtin_amdgcn_global_load_lds(
          (const __attribute__((address_space(1))) unsigned int*)(pA[it] + kt),
          (__attribute__((address_space(3))) unsigned int*)(&smA[buf * 8192 + dA[it]]),
          16, 0, 0);
#pragma unroll
    for (int it = 0; it < 4; ++it)
      __builtin_amdgcn_global_load_lds(
          (const __attribute__((address_space(1))) unsigned int*)(pB[it] + kt),
          (__attribute__((address_space(3))) unsigned int*)(&smB[buf * 8192 + dB[it]]),
          16, 0, 0);
  };

  const int NT = K / BK;                       // 4
  stage(0, 0);
  __syncthreads();
  int cur = 0;
  for (int t = 0; t < NT; ++t) {
    if (t + 1 < NT) stage(cur ^ 1, (t + 1) * BK);
#pragma unroll
    for (int kk = 0; kk < 2; ++kk) {
      f16x8 av[4], bv[4];
#pragma unroll
      for (int i = 0; i < 4; ++i) {
        int row = wr * 64 + i * 16 + lr;
        int ch = (kk * 4 + kq) ^ (lr & 7);
        av[i] = *reinterpret_cast<const f16x8*>(&smA[cur * 8192 + row * BK + ch * 8]);
      }
#pragma unroll
      for (int j = 0; j < 4; ++j) {
        int row = wc * 64 + j * 16 + lr;
        int ch = (kk * 4 + kq) ^ (lr & 7);
        bv[j] = *reinterpret_cast<const f16x8*>(&smB[cur * 8192 + row * BK + ch * 8]);
      }
#pragma unroll
      for (int i = 0; i < 4; ++i)
#pragma unroll
        for (int j = 0; j < 4; ++j)
          acc[i][j] = __builtin_amdgcn_mfma_f32_16x16x32_f16(av[i], bv[j], acc[i][j], 0, 0, 0);
    }
    __syncthreads();
    cur ^= 1;
  }

  const int bp = row0 >> 10, n0 = row0 & 1023;
  if (by < 8) {
#pragma unroll
    for (int i = 0; i < 4; ++i)
#pragma unroll
      for (int j = 0; j < 4; ++j)
#pragma unroll
        for (int q = 0; q < 4; ++q) {
          int t = row0 + wr * 64 + i * 16 + kq * 4 + q;
          int jj = col0 + wc * 64 + j * 16 + lr;
          int part = jj >> 9, inner = jj & 511;
          int h = inner >> 6, d = inner & 63;
          int n = t & 1023;
          size_t img = (size_t)((t >> 10) * 8 + h);
          float v = acc[i][j][q];
          if (part == 0) Q[(img * 1024 + n) * 64 + d] = __float2half(v * 0.125f);
          else           Ko[(img * 1024 + n) * 64 + d] = __float2half(v);
        }
  } else {
#pragma unroll
    for (int i = 0; i < 4; ++i)
#pragma unroll
      for (int j = 0; j < 4; ++j)
#pragma unroll
        for (int q = 0; q < 4; ++q) {
          int nl = wr * 64 + i * 16 + kq * 4 + q;
          int jl = wc * 64 + j * 16 + lr;
          int ch = (nl >> 3) ^ (jl & 7);
          Tld[jl * 136 + ch * 8 + (nl & 7)] = __float2half(acc[i][j][q]);
        }
    __syncthreads();
    const int jl = tid >> 1, hf = tid & 1;
    const int d = jl & 63;
    const int vimg = bp * 8 + (by - 8) * 2 + (jl >> 6);
    __half* dst = Vt + ((size_t)(vimg * 64 + d)) * 1024 + n0 + hf * 64;
#pragma unroll
    for (int u = 0; u < 8; ++u) {
      int cidx = (hf * 8 + u) ^ (jl & 7);
      *reinterpret_cast<u16x8*>(dst + u * 8) =
          *reinterpret_cast<const u16x8*>(Tld + jl * 136 + cidx * 8);
    }
  }
}

// ---------------- out-proj GEMM (generic BT, 4 waves) ----------------
struct EpiOut {
  float* out; const float* bias;
  DEV void store(int, int t, int j, float v) const {
    out[(size_t)t * 256 + j] = v + bias[j];
  }
};

template <int BM, int BN, int BK, int WGN, int FM, int FN, class Epi>
__global__ __launch_bounds__(256) void gemm_bt(
    const __half* __restrict__ A, long long aStride,
    const __half* __restrict__ B, long long bStride,
    int K, Epi epi) {
  constexpr int CPR = BK / 8;
  constexpr int NCA = (BM * BK) / (8 * 256);
  constexpr int NCB = (BN * BK) / (8 * 256);
  constexpr int KSUB = BK / 32;
  __shared__ __align__(16) __half smA[2][BM * BK];
  __shared__ __align__(16) __half smB[2][BN * BK];
  const int tid = threadIdx.x;
  const int lane = tid & 63, wid = tid >> 6;
  const int wr = wid / WGN, wc = wid % WGN;
  const int gx = gridDim.x, gxy = gridDim.x * gridDim.y;
  const int nwg = gxy * gridDim.z;
  const int b_lin = blockIdx.x + blockIdx.y * gx + blockIdx.z * gxy;
  const int logical = (b_lin & 7) * (nwg >> 3) + (b_lin >> 3);
  const int bx = logical % gx, by = (logical / gx) % gridDim.y, bz = logical / gxy;
  const int img = bz;
  const int row0 = bx * BM;
  const int col0 = by * BN;
  const __half* Ab = A + (size_t)((long long)img * aStride);
  const __half* Bb = B + (size_t)((long long)img * bStride);
  f32x4 acc[FM][FN] = {};
  const int lr = lane & 15;
  const int kq = lane >> 4;

  auto swz = [](int c, int r) -> int {
    return (CPR == 8) ? (c ^ (r & 7)) : (c ^ ((r >> 1) & 3));
  };

  const __half* pA[NCA]; int dA[NCA];
  const __half* pB[NCB]; int dB[NCB];
#pragma unroll
  for (int it = 0; it < NCA; ++it) {
    int e = it * 256 + tid, r = e / CPR, c = e % CPR;
    pA[it] = Ab + (size_t)(row0 + r) * K + swz(c, r) * 8;
    dA[it] = r * BK + c * 8;
  }
#pragma unroll
  for (int it = 0; it < NCB; ++it) {
    int e = it * 256 + tid, r = e / CPR, c = e % CPR;
    pB[it] = Bb + (size_t)(col0 + r) * K + swz(c, r) * 8;
    dB[it] = r * BK + c * 8;
  }

  auto stage = [&](int buf, int kt) {
#pragma unroll
    for (int it = 0; it < NCA; ++it)
      __builtin_amdgcn_global_load_lds(
          (const __attribute__((address_space(1))) unsigned int*)(pA[it] + kt),
          (__attribute__((address_space(3))) unsigned int*)(&smA[buf][dA[it]]),
          16, 0, 0);
#pragma unroll
    for (int it = 0; it < NCB; ++it)
      __builtin_amdgcn_global_load_lds(
          (const __attribute__((address_space(1))) unsigned int*)(pB[it] + kt),
          (__attribute__((address_space(3))) unsigned int*)(&smB[buf][dB[it]]),
          16, 0, 0);
  };

  const int NT = K / BK;
  stage(0, 0);
  __syncthreads();
  int cur = 0;
  for (int t = 0; t < NT; ++t) {
    if (t + 1 < NT) stage(cur ^ 1, (t + 1) * BK);
#pragma unroll
    for (int kk = 0; kk < KSUB; ++kk) {
      f16x8 av[FM], bv[FN];
#pragma unroll
      for (int i = 0; i < FM; ++i) {
        int row = wr * FM * 16 + i * 16 + lr;
        int ch = swz(kk * 4 + kq, lr);
        av[i] = *reinterpret_cast<const f16x8*>(&smA[cur][row * BK + ch * 8]);
      }
#pragma unroll
      for (int j = 0; j < FN; ++j) {
        int row = wc * FN * 16 + j * 16 + lr;
        int ch = swz(kk * 4 + kq, lr);
        bv[j] = *reinterpret_cast<const f16x8*>(&smB[cur][row * BK + ch * 8]);
      }
#pragma unroll
      for (int i = 0; i < FM; ++i)
#pragma unroll
        for (int j = 0; j < FN; ++j)
          acc[i][j] = __builtin_amdgcn_mfma_f32_16x16x32_f16(av[i], bv[j], acc[i][j], 0, 0, 0);
    }
    __syncthreads();
    cur ^= 1;
  }

  const int orow = row0 + wr * FM * 16 + (lane >> 4) * 4;
  const int ocol = col0 + wc * FN * 16 + lr;
#pragma unroll
  for (int i = 0; i < FM; ++i)
#pragma unroll
    for (int j = 0; j < FN; ++j)
#pragma unroll
      for (int q = 0; q < 4; ++q)
        epi.store(img, orow + i * 16 + q, ocol + j * 16, acc[i][j][q]);
}

// ---------------- fused QK^T + depthwise convs ----------------
__global__ __launch_bounds__(512) void qkconv_kernel(
    const __half* __restrict__ Q, const __half* __restrict__ Km,
    const float* __restrict__ wc1, const float* __restrict__ wc2,
    __half* __restrict__ AC) {
  constexpr int NP = 132;                       // Dt inner pad (halfs)
  __shared__ __align__(16) char LDS[77824];     // max(stage 48K, Dt 66K) + T 10K
  __half* smA = (__half*)LDS;                   // [128][64]  16384 B
  __half* smB = (__half*)(LDS + 16384);         // [256][64]  32768 B
  __half* Dt  = (__half*)LDS;                   // [256][132] 67584 B (aliases stage)
  __half* T   = (__half*)(LDS + 67584);         // [4][32][40] 10240 B
  const int tid = threadIdx.x;
  const int lane = tid & 63, wid = tid >> 6;
  const int wr = wid >> 2, wc = wid & 3;
  const int gx = gridDim.x, gxy = gx * gridDim.y;
  const int nwg = gxy * gridDim.z;
  const int b_lin = blockIdx.x + blockIdx.y * gx + blockIdx.z * gxy;
  const int logical = (b_lin & 7) * (nwg >> 3) + (b_lin >> 3);
  const int bx = logical % gx, by = (logical / gx) % gridDim.y, bz = logical / gxy;
  const int img = bz, row0 = bx * 128, col0 = by * 256;
  const __half* Qi = Q + ((size_t)img << 16);
  const __half* Ki = Km + ((size_t)img << 16);

#pragma unroll
  for (int it = 0; it < 2; ++it) {
    int e = it * 512 + tid, r = e >> 3, c = e & 7, sc = c ^ (r & 7);
    __builtin_amdgcn_global_load_lds(
        (const __attribute__((address_space(1))) unsigned int*)(Qi + (size_t)(row0 + r) * 64 + sc * 8),
        (__attribute__((address_space(3))) unsigned int*)(smA + r * 64 + c * 8), 16, 0, 0);
  }
#pragma unroll
  for (int it = 0; it < 4; ++it) {
    int e = it * 512 + tid, r = e >> 3, c = e & 7, sc = c ^ (r & 7);
    __builtin_amdgcn_global_load_lds(
        (const __attribute__((address_space(1))) unsigned int*)(Ki + (size_t)(col0 + r) * 64 + sc * 8),
        (__attribute__((address_space(3))) unsigned int*)(smB + r * 64 + c * 8), 16, 0, 0);
  }
  __syncthreads();

  const int lr = lane & 15, kq = lane >> 4;
  f32x4 acc[4][4] = {};
#pragma unroll
  for (int kk = 0; kk < 2; ++kk) {
    const int ch = (kk * 4 + kq) ^ (lr & 7);
    f16x8 av[4], bv[4];
#pragma unroll
    for (int i = 0; i < 4; ++i)
      av[i] = *reinterpret_cast<const f16x8*>(&smA[(wr * 64 + i * 16 + lr) * 64 + ch * 8]);
#pragma unroll
    for (int j = 0; j < 4; ++j)
      bv[j] = *reinterpret_cast<const f16x8*>(&smB[(wc * 64 + j * 16 + lr) * 64 + ch * 8]);
#pragma unroll
    for (int i = 0; i < 4; ++i)
#pragma unroll
      for (int j = 0; j < 4; ++j)
        acc[i][j] = __builtin_amdgcn_mfma_f32_16x16x32_f16(av[i], bv[j], acc[i][j], 0, 0, 0);
  }
  __syncthreads();

#pragma unroll
  for (int i = 0; i < 4; ++i) {
    int n0 = wr * 64 + i * 16 + kq * 4;
#pragma unroll
    for (int j = 0; j < 4; ++j) {
      int m = wc * 64 + j * 16 + lr;
      ushort4 o4;
      o4.x = f2h_bits(acc[i][j][0]); o4.y = f2h_bits(acc[i][j][1]);
      o4.z = f2h_bits(acc[i][j][2]); o4.w = f2h_bits(acc[i][j][3]);
      *reinterpret_cast<ushort4*>(Dt + m * NP + n0) = o4;
    }
  }
  __syncthreads();

  const int w2i = tid >> 7;
  const int b_  = (tid >> 4) & 7;
  const int a_  = (tid >> 2) & 3;
  const int w1q = (tid & 3) * 8;
  const int cch = (bx * 4 + a_) * 32 + (by * 8 + b_);
  const float u0 = wc1[2 * cch], u1 = wc1[2 * cch + 1];
  const float v0 = wc2[2 * cch], v1 = wc2[2 * cch + 1];
  const int cblk = (bx * 4 + by) * 32;
  __half* ACi = AC + ((size_t)img << 20);
  const int w1o = (tid >> 2) & 31, ck = tid & 3;

  for (int pass = 0; pass < 8; ++pass) {
    const int w2 = pass * 4 + w2i;
    const int w2n = (w2 < 31) ? w2 + 1 : 30;
    const __half* r0 = Dt + (b_ * 32 + w2) * NP + a_ * 32 + w1q;
    const __half* r1 = Dt + (b_ * 32 + w2n) * NP + a_ * 32 + w1q;
    float X[9];
    {
      ushort4 x0a = *reinterpret_cast<const ushort4*>(r0);
      ushort4 x0b = *reinterpret_cast<const ushort4*>(r0 + 4);
      ushort4 x1a = *reinterpret_cast<const ushort4*>(r1);
      ushort4 x1b = *reinterpret_cast<const ushort4*>(r1 + 4);
      X[0] = u0 * h2f_bits(x0a.x) + u1 * h2f_bits(x1a.x);
      X[1] = u0 * h2f_bits(x0a.y) + u1 * h2f_bits(x1a.y);
      X[2] = u0 * h2f_bits(x0a.z) + u1 * h2f_bits(x1a.z);
      X[3] = u0 * h2f_bits(x0a.w) + u1 * h2f_bits(x1a.w);
      X[4] = u0 * h2f_bits(x0b.x) + u1 * h2f_bits(x1b.x);
      X[5] = u0 * h2f_bits(x0b.y) + u1 * h2f_bits(x1b.y);
      X[6] = u0 * h2f_bits(x0b.z) + u1 * h2f_bits(x1b.z);
      X[7] = u0 * h2f_bits(x0b.w) + u1 * h2f_bits(x1b.w);
      X[8] = u0 * __half2float(r0[8]) + u1 * __half2float(r1[8]);
    }
#pragma unroll
    for (int k = 0; k < 8; ++k) {
      float ov = (w1q + k < 31) ? (v0 * X[k] + v1 * X[k + 1])
                                : (v0 * X[7] + v1 * X[6]);
      T[(w2i * 32 + w1q + k) * 40 + a_ * 8 + b_] = __float2half(ov);
    }
    __syncthreads();
    {
      const int w2o = pass * 4 + (tid >> 7);
      u16x8 v = *reinterpret_cast<const u16x8*>(T + ((tid >> 7) * 32 + w1o) * 40 + ck * 8);
      *reinterpret_cast<u16x8*>(ACi + (size_t)(w1o * 32 + w2o) * 1024 + cblk + ck * 8) = v;
    }
    __syncthreads();
  }
}

// ---------------- 256x128-tile 8-wave GEMM: 1x1 conv + BN + SiLU + softmax + PV ----------------
__global__ __launch_bounds__(512, 4) void gemm1x1pv(
    const __half* __restrict__ A,
    const __half* __restrict__ B, long long bStride,
    const __half* __restrict__ Vt,
    int K,
    const float* __restrict__ g, const float* __restrict__ b,
    const float* __restrict__ m, const float* __restrict__ vv,
    __half* __restrict__ O) {
  __shared__ __align__(16) char LDSRAW[81920];
  __half* smA = (__half*)LDSRAW;                 // [2][256*32] = 32KB
  __half* smB = (__half*)(LDSRAW + 32768);       // [2][128*32] = 16KB
  __half* Plds = (__half*)LDSRAW;                // [32][1024]  = 64KB (aliases stage)
  __half* Vlds = (__half*)(LDSRAW + 65536);      // [64][128]   = 16KB
  const int tid = threadIdx.x;
  const int lane = tid & 63, wid = tid >> 6;
  const int wr = wid >> 1, wc = wid & 1;         // 4 x 2 waves; wave tile 64x64
  const int gx = gridDim.x, gxy = gx * gridDim.y;
  const int nwg = gxy * gridDim.z;
  const int b_lin = blockIdx.x + blockIdx.y * gx + blockIdx.z * gxy;
  const int logical = (b_lin & 7) * (nwg >> 3) + (b_lin >> 3);
  const int bx = logical % gx, by = (logical / gx) % gridDim.y, bz = logical / gxy;
  const int img = bz, row0 = bx * 256, col0 = by * 128;
  const __half* Ab = A;
  const __half* Bb = B + (size_t)((long long)img * bStride);
  const __half* Vti = Vt + ((size_t)img << 16);

  const __half* pA[2]; int dA[2];
#pragma unroll
  for (int it = 0; it < 2; ++it) {
    int e = it * 512 + tid, r = e >> 2, c = e & 3, sc = c ^ ((r >> 1) & 3);
    pA[it] = Ab + (size_t)(row0 + r) * K + sc * 8;
    dA[it] = r * 32 + c * 8;
  }
  const __half* pB1; int dB1;
  {
    int r = tid >> 2, c = tid & 3, sc = c ^ ((r >> 1) & 3);
    pB1 = Bb + (size_t)(col0 + r) * K + sc * 8;
    dB1 = r * 32 + c * 8;
  }
  auto stage = [&](int buf, int kt) {
#pragma unroll
    for (int it = 0; it < 2; ++it)
      __builtin_amdgcn_global_load_lds(
          (const __attribute__((address_space(1))) unsigned int*)(pA[it] + kt),
          (__attribute__((address_space(3))) unsigned int*)(&smA[buf * 8192 + dA[it]]),
          16, 0, 0);
    __builtin_amdgcn_global_load_lds(
        (const __attribute__((address_space(1))) unsigned int*)(pB1 + kt),
        (__attribute__((address_space(3))) unsigned int*)(&smB[buf * 4096 + dB1]),
        16, 0, 0);
  };
  auto stageV = [&](int ph) {
#pragma unroll
    for (int it = 0; it < 2; ++it) {
      int c = it * 512 + tid;
      int d = c >> 4, col8 = c & 15;
      __builtin_amdgcn_global_load_lds(
          (const __attribute__((address_space(1))) unsigned int*)(Vti + (size_t)d * 1024 + ph * 128 + ((col8 ^ (d & 7)) * 8)),
          (__attribute__((address_space(3))) unsigned int*)(Vlds + c * 8),
          16, 0, 0);
    }
  };

  const int lr = lane & 15, kq = lane >> 4;
  const int ch = kq ^ ((lr >> 1) & 3);
  const int aOff = (wr * 64 + lr) * 32 + ch * 8;
  const int bOff = (wc * 64 + lr) * 32 + ch * 8;
  f32x4 acc[4][4] = {};

  const int NT = K / 32;
  stage(0, 0);
  __syncthreads();
  int cur = 0;
  for (int t = 0; t < NT; ++t) {
    f16x8 av[4], bv[4];
#pragma unroll
    for (int i = 0; i < 4; ++i)
      av[i] = *reinterpret_cast<const f16x8*>(&smA[cur * 8192 + aOff + i * 512]);
#pragma unroll
    for (int j = 0; j < 4; ++j)
      bv[j] = *reinterpret_cast<const f16x8*>(&smB[cur * 4096 + bOff + j * 512]);
    if (t + 1 < NT) stage(cur ^ 1, (t + 1) * 32);
    __builtin_amdgcn_s_setprio(1);
#pragma unroll
    for (int i = 0; i < 4; ++i)
#pragma unroll
      for (int j = 0; j < 4; ++j)
        acc[i][j] = __builtin_amdgcn_mfma_f32_16x16x32_f16(av[i], bv[j], acc[i][j], 0, 0, 0);
    __builtin_amdgcn_s_setprio(0);
    __syncthreads();
    cur ^= 1;
  }
  stageV(0);   // V phase-0: L2 latency hides under softmax
  const int ob = row0 + wr * 64;
#pragma unroll
  for (int ih = 0; ih < 2; ++ih) {
#pragma unroll
    for (int sh = 0; sh < 2; ++sh) {
      float v[2][2][4];
      float mx = -1e30f;
#pragma unroll
      for (int di = 0; di < 2; ++di) {
        int i = ih * 2 + di;
#pragma unroll
        for (int q = 0; q < 4; ++q) {
          int o = ob + i * 16 + kq * 4 + q;
          float sc = rsqrtf(vv[o] + 1e-5f) * g[o];
          float mo = m[o], bo = b[o];
#pragma unroll
          for (int dj = 0; dj < 2; ++dj) {
            float t = (acc[i][sh * 2 + dj][q] - mo) * sc + bo;
            t = t / (1.f + __expf(-t));       // SiLU
            v[di][dj][q] = t;
            mx = fmaxf(mx, t);
          }
        }
      }
#pragma unroll
      for (int off = 32; off; off >>= 1) mx = fmaxf(mx, __shfl_xor(mx, off));
      float sm = 0.f;
#pragma unroll
      for (int di = 0; di < 2; ++di)
#pragma unroll
        for (int dj = 0; dj < 2; ++dj)
#pragma unroll
          for (int q = 0; q < 4; ++q) {
            float e = __expf(v[di][dj][q] - mx);
            v[di][dj][q] = e; sm += e;
          }
#pragma unroll
      for (int off = 32; off; off >>= 1) sm += __shfl_xor(sm, off);
      float inv = 1.f / sm;
      const int ri = (wr * 2 + ih) * 4 + wc * 2 + sh;      // P row 0..31
      const int sw = (ri & 7) << 3;
      __half* Prow = Plds + ri * 1024;
#pragma unroll
      for (int di = 0; di < 2; ++di)
#pragma unroll
        for (int q = 0; q < 4; ++q) {
          int mo_ = (di * 16 + kq * 4 + q) * 32;
#pragma unroll
          for (int dj = 0; dj < 2; ++dj) {
            int mm = mo_ + dj * 16 + lr;
            Prow[mm ^ sw] = __float2half(v[di][dj][q] * inv);
          }
        }
    }
  }
  __syncthreads();
  {
    const int rt = wid >> 2, dt = wid & 3;
    const int arow = rt * 16 + lr;
    const int asw = (arow & 7) << 3;
    const int d = dt * 16 + lr;
    const __half* Pr = Plds + arow * 1024;
    const __half* Vr = Vlds + d * 128;
    f32x4 acc2 = {};
    for (int ph = 0; ph < 8; ++ph) {
#pragma unroll
      for (int kk2 = 0; kk2 < 4; ++kk2) {
        int m0 = ph * 128 + kk2 * 32 + kq * 8;
        f16x8 a = *reinterpret_cast<const f16x8*>(&Pr[m0 ^ asw]);
        f16x8 bb = *reinterpret_cast<const f16x8*>(&Vr[((kk2 * 4 + kq) ^ (d & 7)) * 8]);
        acc2 = __builtin_amdgcn_mfma_f32_16x16x32_f16(a, bb, acc2, 0, 0, 0);
      }
      if (ph < 7) {
        __syncthreads();
        stageV(ph + 1);
        __syncthreads();
      }
    }
#pragma unroll
    for (int q = 0; q < 4; ++q) {
      int ri = rt * 16 + kq * 4 + q;
      int n = (bx * 8 + (ri >> 2)) * 32 + by * 4 + (ri & 3);
      int dd = dt * 16 + lr;
      O[((size_t)((img >> 3) * 1024 + n)) * 512 + (img & 7) * 64 + dd] = __float2half(acc2[q]);
    }
  }
}

extern "C" void kernel_launch(void* const* d_in, const int* in_sizes, int n_in,
                              void* d_out, int out_size, void* d_ws, size_t ws_size,
                              hipStream_t stream) {
  const float* x     = (const float*)d_in[0];
  const float* ln_g  = (const float*)d_in[1];
  const float* ln_b  = (const float*)d_in[2];
  const float* w_qkv = (const float*)d_in[3];
  const float* wc1   = (const float*)d_in[4];
  const float* wc2   = (const float*)d_in[5];
  const float* w1x1  = (const float*)d_in[6];
  const float* bn_g  = (const float*)d_in[7];
  const float* bn_b  = (const float*)d_in[8];
  const float* bn_m  = (const float*)d_in[9];
  const float* bn_v  = (const float*)d_in[10];
  const float* w_out = (const float*)d_in[11];
  const float* b_out = (const float*)d_in[12];
  float* out = (float*)d_out;

  const size_t MB = 1024 * 1024;
  char* ws = (char*)d_ws;
  __half* ACb = (__half*)(ws + 64 * MB);      // region1 (64MB): AC (permuted channels)
  char* p = ws + 128 * MB;
  __half* XN    = (__half*)p; p += 2 * MB;            // 4096x256
  __half* WQKVT = (__half*)p; p += 1536 * 256 * 2;    // 1536x256
  __half* W1X1H = (__half*)p; p += 2 * MB;            // 1024x1024 (K permuted)
  __half* WOTT  = (__half*)p; p += 256 * 512 * 2;     // 256x512
  __half* Qb    = (__half*)p; p += 4 * MB;            // 32x1024x64 (scaled)
  __half* Kb    = (__half*)p; p += 4 * MB;            // 32x1024x64
  __half* Vtb   = (__half*)p; p += 4 * MB;            // 32x64x1024
  __half* Ob    = (__half*)p; p += 4 * MB;            // 4096x512

  prep_kernel<<<1024, 256, 0, stream>>>(w1x1, W1X1H);
  tcast_kernel<<<dim3(4, 24), 256, 0, stream>>>(w_qkv, WQKVT, 256, 1536);
  tcast_kernel<<<dim3(8, 4), 256, 0, stream>>>(w_out, WOTT, 512, 256);
  ln_kernel<<<4096, 256, 0, stream>>>(x, ln_g, ln_b, XN);

  gemm_qkv<<<dim3(32, 12), 256, 0, stream>>>(XN, WQKVT, Qb, Kb, Vtb);

  qkconv_kernel<<<dim3(8, 4, 32), 512, 0, stream>>>(Qb, Kb, wc1, wc2, ACb);

  gemm1x1pv<<<dim3(4, 8, 32), 512, 0, stream>>>(
      W1X1H, ACb, 1 << 20, Vtb, 1024, bn_g, bn_b, bn_m, bn_v, Ob);

  { EpiOut e{out, b_out};
    gemm_bt<64, 64, 64, 2, 2, 2, EpiOut><<<dim3(64, 4, 1), 256, 0, stream>>>(
        Ob, 0, WOTT, 0, 512, e); }
}